// Round 9
// baseline (371.393 us; speedup 1.0000x reference)
//
#include <hip/hip_runtime.h>

#define DM   1024
#define DFF  4096
#define NH   16
#define HD   64
#define TT   2048
#define BT   4096   // B*T
#define KC   5120   // concat-K: 1024 (attn_o) + 4096 (ff1)

typedef unsigned short u16;
typedef unsigned int   u32;
typedef __attribute__((ext_vector_type(8))) short s16x8;
typedef __attribute__((ext_vector_type(4))) float f32x4;

__device__ __forceinline__ u16 f2bf(float f) {
  u32 u = __builtin_bit_cast(u32, f);
  u += 0x7fffu + ((u >> 16) & 1u);
  return (u16)(u >> 16);
}

// async global->LDS, 16B per lane. HW semantics: dest = wave-uniform base + lane*16.
__device__ __forceinline__ void gl2lds16(const void* g, void* l) {
  __builtin_amdgcn_global_load_lds((__attribute__((address_space(1))) void*)(g),
                                   (__attribute__((address_space(3))) void*)(l),
                                   16, 0, 0);
}

// raw barrier (no vmcnt(0) drain) + scheduler pin
#define S_BARRIER() do { __builtin_amdgcn_s_barrier(); __builtin_amdgcn_sched_barrier(0); } while (0)
#define VMWAIT(n)   asm volatile("s_waitcnt vmcnt(" #n ")" ::: "memory")

// ---------------- RMSNorm: x fp32 [BT][DM] -> xn bf16 ----------------
__global__ __launch_bounds__(256) void rmsnorm_k(const float* __restrict__ x,
                                                 const float* __restrict__ w,
                                                 u16* __restrict__ xn) {
  const int row = blockIdx.x;
  const int t = threadIdx.x;
  const float4 v = ((const float4*)(x + (size_t)row * DM))[t];
  float ss = v.x*v.x + v.y*v.y + v.z*v.z + v.w*v.w;
  #pragma unroll
  for (int off = 32; off; off >>= 1) ss += __shfl_xor(ss, off, 64);
  __shared__ float red[4];
  if ((t & 63) == 0) red[t >> 6] = ss;
  __syncthreads();
  const float tot = red[0] + red[1] + red[2] + red[3];
  const float r = __builtin_amdgcn_rsqf(tot * (1.0f / DM) + 1.1920929e-7f);
  const float4 wv = ((const float4*)w)[t];
  u16* o = xn + (size_t)row * DM + t * 4;
  o[0] = f2bf(v.x * r * wv.x);
  o[1] = f2bf(v.y * r * wv.y);
  o[2] = f2bf(v.z * r * wv.z);
  o[3] = f2bf(v.w * r * wv.w);
}

// --- weight transpose+cvt: W fp32 [K][N] -> Wt bf16 [n][pitch] at col-offset koff ---
__global__ __launch_bounds__(256) void wtrans_k(const float* __restrict__ W,
                                                u16* __restrict__ Wt,
                                                int K, int N, int pitch, int koff) {
  __shared__ float tile[32][33];
  const int n0 = blockIdx.x * 32, k0 = blockIdx.y * 32;
  const int tx = threadIdx.x, ty = threadIdx.y;  // (32,8)
  #pragma unroll
  for (int i = 0; i < 4; ++i)
    tile[ty + i*8][tx] = W[(size_t)(k0 + ty + i*8) * N + n0 + tx];
  __syncthreads();
  #pragma unroll
  for (int i = 0; i < 4; ++i)
    Wt[(size_t)(n0 + ty + i*8) * pitch + koff + k0 + tx] = f2bf(tile[tx][ty + i*8]);
}

// ---- fused QKV+FFN1 GEMM: A=xn [4096][1024], Bt [7168][1024] ----
// R3: m201-style 8-phase schedule. BM=BN=256, BK=64, 512 thr / 8 waves (2Mx4N),
// wave tile 128x64. LDS = 2 slots x 2 halves x [128][64] u16 per operand = 128 KiB.
// Per phase: {ds_read quadrant frags | 2x gl2lds (one half-tile) | barrier |
// setprio(1) 16 MFMA setprio(0) | counted VMWAIT | barrier}. 8 phases = 2 K-tiles.
// vmcnt never 0 in steady state: VM(4) at ph2/ph6, VM(2) at ph4/ph8.
// R8: identity block mapping (R4's XCD swizzle measured WORSE: FETCH 63->115 MB).
__global__ __launch_bounds__(512, 2) void gemm_fused(const u16* __restrict__ A,
                                                     const u16* __restrict__ Bt,
                                                     u16* __restrict__ qkb,
                                                     u16* __restrict__ vtg,
                                                     u16* __restrict__ acat) {
  const int K = 1024;
  __shared__ u16 sA[2 * 16384];   // [slot][half][sub][64 rows][8 chunks][8 u16] = 64 KB
  __shared__ u16 sB[2 * 16384];   // 64 KB
  const int t = threadIdx.x;               // 0..511
  const int lane = t & 63, wave = t >> 6;  // 8 waves
  const int quad = lane >> 4, l4 = lane & 15;
  const int wy = wave >> 2, wx = wave & 3; // wave grid 2(M) x 4(N); wave tile 128x64
  const size_t mBase = (size_t)blockIdx.y * 256;
  const size_t nBase = (size_t)blockIdx.x * 256;

  // staging: G-load g covers tile rows g*64..g*64+63; thread t -> row t>>3,
  // pre-swizzled source chunk (t&7)^(row&7)
  const int grow = t >> 3;                       // 0..63
  const int gchk = ((t & 7) ^ (grow & 7)) * 8;   // u16 offset in 64-elem row
  const u16* AgR = A  + (mBase + grow) * K + gchk;
  const u16* BgR = Bt + (nBase + grow) * K + gchk;
  char* dA = (char*)sA;
  char* dB = (char*)sB;
  const int woff = wave * 1024;                  // per-wave dest offset in a G-load

  // read-side swizzled chunk offsets (u16 units), per-lane constants
  const int cs0 = ((quad)     ^ (l4 & 7)) * 8;   // kk=0
  const int cs1 = ((4 + quad) ^ (l4 & 7)) * 8;   // kk=1

  f32x4 acc[8][4];
  #pragma unroll
  for (int i = 0; i < 8; ++i)
    #pragma unroll
    for (int j = 0; j < 4; ++j)
      acc[i][j] = (f32x4)0.0f;

  s16x8 a[4][2], b[4][2];

  // stage phase p (0..3) of K-tile kt into slot: p0={Bg0,Bg1} p1={Bg2,Bg3}
  // p2={Ag0,Ag2} p3={Ag1,Ag3}; G-load g -> LDS byte (g>>1)*16384 + (g&1)*8192
  #define STG(p, slot, kt) do {                                                  \
    const int k0_ = (kt) * 64;                                                   \
    if ((p) == 0) {                                                              \
      gl2lds16(BgR + (size_t)0*64*K + k0_, dB + (slot)*32768 +     0 + woff);    \
      gl2lds16(BgR + (size_t)1*64*K + k0_, dB + (slot)*32768 +  8192 + woff);    \
    } else if ((p) == 1) {                                                       \
      gl2lds16(BgR + (size_t)2*64*K + k0_, dB + (slot)*32768 + 16384 + woff);    \
      gl2lds16(BgR + (size_t)3*64*K + k0_, dB + (slot)*32768 + 24576 + woff);    \
    } else if ((p) == 2) {                                                       \
      gl2lds16(AgR + (size_t)0*64*K + k0_, dA + (slot)*32768 +     0 + woff);    \
      gl2lds16(AgR + (size_t)2*64*K + k0_, dA + (slot)*32768 + 16384 + woff);    \
    } else {                                                                     \
      gl2lds16(AgR + (size_t)1*64*K + k0_, dA + (slot)*32768 +  8192 + woff);    \
      gl2lds16(AgR + (size_t)3*64*K + k0_, dA + (slot)*32768 + 24576 + woff);    \
    }                                                                            \
  } while (0)

  // read A-frags for quadrant qm of slot (8 ds_read_b128)
  #define RDA(slot, qm) do {                                                     \
    const u16* p_ = sA + (slot)*16384 + wy*8192;                                 \
    _Pragma("unroll")                                                            \
    for (int m_ = 0; m_ < 4; ++m_) {                                             \
      const int ro_ = (((qm)*4 + m_)*16 + l4) * 64;                              \
      a[m_][0] = *(const s16x8*)&p_[ro_ + cs0];                                  \
      a[m_][1] = *(const s16x8*)&p_[ro_ + cs1];                                  \
    }                                                                            \
  } while (0)

  // read B-frags for quadrant qn of slot (4 ds_read_b128)
  #define RDB(slot, qn) do {                                                     \
    const u16* p_ = sB + (slot)*16384 + (wx>>1)*8192 + (wx&1)*4096;              \
    _Pragma("unroll")                                                            \
    for (int n_ = 0; n_ < 2; ++n_) {                                             \
      const int ro_ = (((qn)*2 + n_)*16 + l4) * 64;                              \
      b[(qn)*2 + n_][0] = *(const s16x8*)&p_[ro_ + cs0];                         \
      b[(qn)*2 + n_][1] = *(const s16x8*)&p_[ro_ + cs1];                         \
    }                                                                            \
  } while (0)

  // 16 MFMA for quadrant (qm,qn)
  #define MM(qm, qn) do {                                                        \
    __builtin_amdgcn_s_setprio(1);                                               \
    _Pragma("unroll")                                                            \
    for (int m_ = 0; m_ < 4; ++m_)                                               \
      _Pragma("unroll")                                                          \
      for (int n_ = 0; n_ < 2; ++n_) {                                           \
        acc[(qm)*4+m_][(qn)*2+n_] = __builtin_amdgcn_mfma_f32_16x16x32_bf16(     \
            a[m_][0], b[(qn)*2+n_][0], acc[(qm)*4+m_][(qn)*2+n_], 0, 0, 0);      \
        acc[(qm)*4+m_][(qn)*2+n_] = __builtin_amdgcn_mfma_f32_16x16x32_bf16(     \
            a[m_][1], b[(qn)*2+n_][1], acc[(qm)*4+m_][(qn)*2+n_], 0, 0, 0);      \
      }                                                                          \
    __builtin_amdgcn_s_setprio(0);                                               \
  } while (0)

  // prologue: stage tile 0 -> slot 0
  STG(0, 0, 0); STG(1, 0, 0); STG(2, 0, 0); STG(3, 0, 0);
  VMWAIT(2);       // tile0 p0,p1,p2 landed (A g1,g3 may fly until ph3)
  S_BARRIER();

  // main: 7 iters; iter i computes tiles 2i (slot0) & 2i+1 (slot1),
  // stages tile 2i+1 -> slot1 (ph1-4) and tile 2i+2 -> slot0 (ph5-8)
  for (int i = 0; i < 7; ++i) {
    const int kt1 = 2*i + 1, kt2 = 2*i + 2;
    RDA(0,0); RDB(0,0); STG(0,1,kt1); S_BARRIER(); MM(0,0);            S_BARRIER();
    RDB(0,1);           STG(1,1,kt1); S_BARRIER(); MM(0,1); VMWAIT(4); S_BARRIER();
    RDA(0,1);           STG(2,1,kt1); S_BARRIER(); MM(1,0);            S_BARRIER();
                        STG(3,1,kt1); S_BARRIER(); MM(1,1); VMWAIT(2); S_BARRIER();
    RDA(1,0); RDB(1,0); STG(0,0,kt2); S_BARRIER(); MM(0,0);            S_BARRIER();
    RDB(1,1);           STG(1,0,kt2); S_BARRIER(); MM(0,1); VMWAIT(4); S_BARRIER();
    RDA(1,1);           STG(2,0,kt2); S_BARRIER(); MM(1,0);            S_BARRIER();
                        STG(3,0,kt2); S_BARRIER(); MM(1,1); VMWAIT(2); S_BARRIER();
  }
  // epilogue iter: tiles 14 (slot0) & 15 (slot1); no staging past tile 15
  RDA(0,0); RDB(0,0); STG(0,1,15); S_BARRIER(); MM(0,0);            S_BARRIER();
  RDB(0,1);           STG(1,1,15); S_BARRIER(); MM(0,1); VMWAIT(4); S_BARRIER();
  RDA(0,1);           STG(2,1,15); S_BARRIER(); MM(1,0);            S_BARRIER();
                      STG(3,1,15); S_BARRIER(); MM(1,1); VMWAIT(2); S_BARRIER();
  RDA(1,0); RDB(1,0);              S_BARRIER(); MM(0,0);            S_BARRIER();
  RDB(1,1);                        S_BARRIER(); MM(0,1); VMWAIT(0); S_BARRIER();
  RDA(1,1);                        S_BARRIER(); MM(1,0);            S_BARRIER();
                                   S_BARRIER(); MM(1,1);            S_BARRIER();

  #undef STG
  #undef RDA
  #undef RDB
  #undef MM

  // block-uniform region select (boundaries 1024/2048/3072 are 256-aligned)
  #pragma unroll
  for (int i = 0; i < 8; ++i) {
    const size_t row0 = mBase + wy*128 + i*16 + quad*4;
    #pragma unroll
    for (int j = 0; j < 4; ++j) {
      const int col = (int)nBase + wx*64 + j*16 + l4;
      if (nBase < 1024) {               // Q: fold (1/sqrt(64))*log2(e)
        #pragma unroll
        for (int rg = 0; rg < 4; ++rg)
          qkb[(row0 + rg) * 2048 + col] = f2bf(acc[i][j][rg] * 0.18033688011f);
      } else if (nBase < 2048) {        // K
        #pragma unroll
        for (int rg = 0; rg < 4; ++rg)
          qkb[(row0 + rg) * 2048 + col] = f2bf(acc[i][j][rg]);
      } else if (nBase < 3072) {        // V: transposed, 4 tokens packed
        const int cv = col - 2048, hh = cv >> 6, dd = cv & 63;
        const int bb = (int)(row0 >> 11), t0 = (int)(row0 & 2047);
        ushort4 pk;
        pk.x = f2bf(acc[i][j][0]); pk.y = f2bf(acc[i][j][1]);
        pk.z = f2bf(acc[i][j][2]); pk.w = f2bf(acc[i][j][3]);
        *(ushort4*)(vtg + ((size_t)((bb*16 + hh)*64 + dd)) * 2048 + t0) = pk;
      } else {                          // FFN1: silu -> A_cat cols 1024..5119
        #pragma unroll
        for (int rg = 0; rg < 4; ++rg) {
          float v = acc[i][j][rg];
          v = v / (1.0f + __expf(-v));
          acat[(row0 + rg) * (size_t)KC + 1024 + (col - 3072)] = f2bf(v);
        }
      }
    }
  }
}

// ---- final GEMM: d_out = x + A_cat[4096][5120] * B_cat[1024][5120]^T ----
// R9: LDS-reuse fix. R8 counters proved final is LDS-THROUGHPUT-bound
// (FETCH 177->70 MB and 6-slot deep ring both changed dur 94->95 not at all;
// 48 ds_read_b128 + 24 KB writes/CU-iter ~= the whole 712-cyc iter budget).
// Old 32x64 wave tile = 1125 B LDS-read/MFMA. New m97 geometry: block tile
// 128x128, 4 waves (2x2), wave tile 64x64, acc[4][4] -> 8 reads/16 MFMA
// = 500 B/MFMA (2.25x less read traffic). Grid 8x32 = 256 blocks = 1/CU.
// 6-slot counted ring kept (4 loads/wave/iter -> steady VMWAIT(16)); 96 KB LDS.
// XCD M-chunk swizzle rescaled (256%8==0): each XCD 4 contiguous M-panels.
__global__ __launch_bounds__(256) void gemm_final(const u16* __restrict__ A,
                                                  const u16* __restrict__ Bt,
                                                  const float* __restrict__ x,
                                                  float* __restrict__ out) {
  __shared__ u16 sA[6 * 128 * 32];   // 48 KB
  __shared__ u16 sB[6 * 128 * 32];   // 48 KB
  const int t = threadIdx.x;
  const int lane = t & 63, wave = t >> 6;
  const int quad = lane >> 4, l4 = lane & 15;
  const int wy = wave >> 1, wx = wave & 1;   // 2x2 wave grid; wave tile 64(M)x64(N)
  const int d  = blockIdx.x + (blockIdx.y << 3);   // 0..255 ; grid (8,32)
  const int vb = ((d & 7) << 5) | (d >> 3);        // bijective: XCD d%8 -> 32 contiguous
  const int bx = vb & 7, by = vb >> 3;
  const size_t mBase = (size_t)by * 128;
  const size_t nBase = (size_t)bx * 128;
  const int r  = t >> 2;          // 0..63 (row within 64-row G-load line)
  const int c8 = ((t & 3) ^ ((t >> 3) & 3)) * 8;   // pre-swizzled source chunk
  const int qsw = (quad ^ ((l4 >> 1) & 3)) * 8;    // swizzled read offset
  const u16* Ag0 = A  + (mBase + r) * KC + c8;
  const u16* Ag1 = Ag0 + (size_t)64 * KC;
  const u16* Bg0 = Bt + (nBase + r) * KC + c8;
  const u16* Bg1 = Bg0 + (size_t)64 * KC;
  char* sAb = (char*)sA + (wave << 10);
  char* sBb = (char*)sB + (wave << 10);

  f32x4 acc[4][4];
  #pragma unroll
  for (int i = 0; i < 4; ++i)
    #pragma unroll
    for (int j = 0; j < 4; ++j)
      acc[i][j] = (f32x4)0.0f;

  auto issue = [&](int sl, int k0) {
    gl2lds16(Ag0 + k0, sAb + sl*8192);           // rows 0..63
    gl2lds16(Ag1 + k0, sAb + sl*8192 + 4096);    // rows 64..127
    gl2lds16(Bg0 + k0, sBb + sl*8192);
    gl2lds16(Bg1 + k0, sBb + sl*8192 + 4096);
  };

  auto compute = [&](int sl) {
    const u16* pA = sA + sl * 4096;   // u16 elements: 128*32
    const u16* pB = sB + sl * 4096;
    s16x8 af[4], bfr[4];
    #pragma unroll
    for (int i = 0; i < 4; ++i)
      af[i] = *(const s16x8*)&pA[(wy*64 + i*16 + l4) * 32 + qsw];
    #pragma unroll
    for (int j = 0; j < 4; ++j)
      bfr[j] = *(const s16x8*)&pB[(wx*64 + j*16 + l4) * 32 + qsw];
    __builtin_amdgcn_s_setprio(1);
    #pragma unroll
    for (int i = 0; i < 4; ++i)
      #pragma unroll
      for (int j = 0; j < 4; ++j)
        acc[i][j] = __builtin_amdgcn_mfma_f32_16x16x32_bf16(af[i], bfr[j], acc[i][j], 0, 0, 0);
    __builtin_amdgcn_s_setprio(0);
  };

  const int NIT = KC / 32;   // 160
  issue(0, 0); issue(1, 32); issue(2, 64); issue(3, 96); issue(4, 128);
  int sl = 0;
  for (int kt = 0; kt < NIT - 5; ++kt) {
    VMWAIT(16);                   // tile kt's 4 loads (mine) landed; 4 tiles in flight
    S_BARRIER();                  // everyone's landed; everyone done reading slot (kt+5)%6
    issue(sl == 0 ? 5 : sl - 1, (kt + 5) * 32);
    compute(sl);
    sl = (sl == 5) ? 0 : sl + 1;
  }
  VMWAIT(16); S_BARRIER(); compute(sl); sl = (sl == 5) ? 0 : sl + 1;
  VMWAIT(12); S_BARRIER(); compute(sl); sl = (sl == 5) ? 0 : sl + 1;
  VMWAIT(8);  S_BARRIER(); compute(sl); sl = (sl == 5) ? 0 : sl + 1;
  VMWAIT(4);  S_BARRIER(); compute(sl); sl = (sl == 5) ? 0 : sl + 1;
  VMWAIT(0);  S_BARRIER(); compute(sl);

  #pragma unroll
  for (int i = 0; i < 4; ++i) {
    const size_t row0 = mBase + wy*64 + i*16 + quad*4;
    #pragma unroll
    for (int j = 0; j < 4; ++j) {
      const int col = (int)nBase + wx*64 + j*16 + l4;
      #pragma unroll
      for (int rg = 0; rg < 4; ++rg) {
        const size_t idx = (row0 + rg) * (size_t)DM + col;
        out[idx] = x[idx] + acc[i][j][rg];
      }
    }
  }
}

// ------- causal flash attention, fixed-max, in-block split-K=2 over waves -------
// writes bf16 into A_cat cols 0..1023 (pitch 5120)
__global__ __launch_bounds__(128) void attn_k(const u16* __restrict__ qk,
                                              const u16* __restrict__ vtg,
                                              u16* __restrict__ acat) {
  const int bh = blockIdx.x, b = bh >> 4, h = bh & 15;
  const int qt = 63 - blockIdx.y;
  const int qw = qt * 32;
  const int wave = threadIdx.x >> 6, lane = threadIdx.x & 63;
  const int quad = lane >> 4, l4 = lane & 15;
  const u16* Qp = qk + (size_t)b * TT * 2048 + h * HD;
  const u16* Kp = Qp + 1024;
  const u16* Vp = vtg + (size_t)bh * 64 * 2048;

  __shared__ u16 Pb[2][32][72];
  __shared__ float Ob[32][68];
  __shared__ float Lb[32];

  s16x8 qf[2][2];
  #pragma unroll
  for (int mi = 0; mi < 2; ++mi)
    #pragma unroll
    for (int kf = 0; kf < 2; ++kf)
      qf[mi][kf] = *(const s16x8*)(Qp + (size_t)(qw + mi*16 + l4) * 2048 + kf*32 + quad*8);

  const s16x8 ones = {0x3F80,0x3F80,0x3F80,0x3F80,0x3F80,0x3F80,0x3F80,0x3F80};

  f32x4 o[2][4];
  f32x4 lacc[2];
  #pragma unroll
  for (int mi = 0; mi < 2; ++mi) {
    lacc[mi] = (f32x4)0.0f;
    #pragma unroll
    for (int ni = 0; ni < 4; ++ni) o[mi][ni] = (f32x4)0.0f;
  }

  const int n   = (qt + 2) >> 1;
  const int n0  = (n + 1) >> 1;
  const int kt0 = wave ? n0 : 0;
  const int kt1 = wave ? n : n0;

  for (int kt = kt0; kt < kt1; ++kt) {
    const int k0 = kt * 64;

    f32x4 st[4][2];
    #pragma unroll
    for (int nj = 0; nj < 4; ++nj) {
      const u16* kr = Kp + (size_t)(k0 + nj*16 + l4) * 2048 + quad*8;
      const s16x8 kf0 = *(const s16x8*)kr;
      const s16x8 kf1 = *(const s16x8*)(kr + 32);
      #pragma unroll
      for (int mi = 0; mi < 2; ++mi) {
        f32x4 a = (f32x4)0.0f;
        a = __builtin_amdgcn_mfma_f32_16x16x32_bf16(kf0, qf[mi][0], a, 0, 0, 0);
        a = __builtin_amdgcn_mfma_f32_16x16x32_bf16(kf1, qf[mi][1], a, 0, 0, 0);
        st[nj][mi] = a;
      }
    }

    s16x8 vb[2][4];
    #pragma unroll
    for (int kf2 = 0; kf2 < 2; ++kf2)
      #pragma unroll
      for (int ni = 0; ni < 4; ++ni)
        vb[kf2][ni] = *(const s16x8*)(Vp + (size_t)(ni*16 + l4) * 2048 + k0 + kf2*32 + quad*8);

    if (k0 + 63 > qw) {
      #pragma unroll
      for (int nj = 0; nj < 4; ++nj)
        #pragma unroll
        for (int mi = 0; mi < 2; ++mi)
          #pragma unroll
          for (int rg = 0; rg < 4; ++rg) {
            const int key = k0 + nj*16 + quad*4 + rg;
            const int q   = qw + mi*16 + l4;
            if (key > q) st[nj][mi][rg] = -1e30f;
          }
    }

    #pragma unroll
    for (int nj = 0; nj < 4; ++nj)
      #pragma unroll
      for (int mi = 0; mi < 2; ++mi) {
        float p0 = __builtin_amdgcn_exp2f(st[nj][mi][0]);
        float p1 = __builtin_amdgcn_exp2f(st[nj][mi][1]);
        float p2 = __builtin_amdgcn_exp2f(st[nj][mi][2]);
        float p3 = __builtin_amdgcn_exp2f(st[nj][mi][3]);
        uint2 w;
        w.x = __builtin_amdgcn_perm(__builtin_bit_cast(u32, p1),
                                    __builtin_bit_cast(u32, p0), 0x07060302u);
        w.y = __builtin_amdgcn_perm(__builtin_bit_cast(u32, p3),
                                    __builtin_bit_cast(u32, p2), 0x07060302u);
        *(uint2*)&Pb[wave][mi*16 + l4][nj*16 + quad*4] = w;
      }

    #pragma unroll
    for (int kf2 = 0; kf2 < 2; ++kf2) {
      s16x8 pa[2];
      #pragma unroll
      for (int mi = 0; mi < 2; ++mi)
        pa[mi] = *(const s16x8*)&Pb[wave][mi*16 + l4][kf2*32 + quad*8];
      #pragma unroll
      for (int mi = 0; mi < 2; ++mi) {
        lacc[mi] = __builtin_amdgcn_mfma_f32_16x16x32_bf16(pa[mi], ones, lacc[mi], 0, 0, 0);
        #pragma unroll
        for (int ni = 0; ni < 4; ++ni)
          o[mi][ni] = __builtin_amdgcn_mfma_f32_16x16x32_bf16(pa[mi], vb[kf2][ni], o[mi][ni], 0, 0, 0);
      }
    }
  }

  if (wave == 1) {
    #pragma unroll
    for (int mi = 0; mi < 2; ++mi)
      #pragma unroll
      for (int rg = 0; rg < 4; ++rg) {
        const int row = mi*16 + quad*4 + rg;
        #pragma unroll
        for (int ni = 0; ni < 4; ++ni) Ob[row][ni*16 + l4] = o[mi][ni][rg];
        if (l4 == 0) Lb[row] = lacc[mi][rg];
      }
  }
  __syncthreads();
  if (wave == 0) {
    #pragma unroll
    for (int mi = 0; mi < 2; ++mi)
      #pragma unroll
      for (int rg = 0; rg < 4; ++rg) {
        const int row = mi*16 + quad*4 + rg;
        const float inv = 1.0f / (lacc[mi][rg] + Lb[row]);
        #pragma unroll
        for (int ni = 0; ni < 4; ++ni)
          Pb[0][row][ni*16 + l4] = f2bf((o[mi][ni][rg] + Ob[row][ni*16 + l4]) * inv);
      }
    #pragma unroll
    for (int it = 0; it < 4; ++it) {
      const int row = it*8 + (lane >> 3);
      const int c0  = (lane & 7) * 8;
      const s16x8 pk = *(const s16x8*)&Pb[0][row][c0];
      *(s16x8*)(acat + ((size_t)b * TT + qw + row) * KC + h*HD + c0) = pk;
    }
  }
}

extern "C" void kernel_launch(void* const* d_in, const int* in_sizes, int n_in,
                              void* d_out, int out_size, void* d_ws, size_t ws_size,
                              hipStream_t stream) {
  (void)in_sizes; (void)n_in; (void)out_size; (void)ws_size;
  const float* x  = (const float*)d_in[0];
  const float* nw = (const float*)d_in[1];
  const float* Wq = (const float*)d_in[2];
  const float* Wk = (const float*)d_in[3];
  const float* Wv = (const float*)d_in[4];
  const float* Wo = (const float*)d_in[5];
  const float* W1 = (const float*)d_in[6];
  const float* W2 = (const float*)d_in[7];

  char* ws = (char*)d_ws;
  u16*   xn      = (u16*)(ws);                          //  8 MB  [4096][1024]
  u16*   wqkv1_t = (u16*)(ws + ((size_t)8  << 20));     // 14 MB  [7168][1024] Wq|Wk|Wv|W1 ^T
  u16*   bcat    = (u16*)(ws + ((size_t)22 << 20));     // 10 MB  [1024][5120] Wo^T|W2^T
  u16*   qkb     = (u16*)(ws + ((size_t)32 << 20));     // 16 MB  [4096][2048] (q|k)
  u16*   vtg     = (u16*)(ws + ((size_t)48 << 20));     //  8 MB  [32][64][2048] V^T
  u16*   acat    = (u16*)(ws + ((size_t)56 << 20));     // 40 MB  [4096][5120] attn_o|ff1
  float* dout    = (float*)d_out;                       // 16 MB  [4096][1024] fp32

  rmsnorm_k<<<BT, 256, 0, stream>>>(x, nw, xn);
  const dim3 tb(32, 8);
  wtrans_k<<<dim3(32, 32),  tb, 0, stream>>>(Wq, wqkv1_t,                      1024, 1024, 1024, 0);
  wtrans_k<<<dim3(32, 32),  tb, 0, stream>>>(Wk, wqkv1_t + (size_t)1024*1024,  1024, 1024, 1024, 0);
  wtrans_k<<<dim3(32, 32),  tb, 0, stream>>>(Wv, wqkv1_t + (size_t)2048*1024,  1024, 1024, 1024, 0);
  wtrans_k<<<dim3(128, 32), tb, 0, stream>>>(W1, wqkv1_t + (size_t)3072*1024,  1024, 4096, 1024, 0);
  wtrans_k<<<dim3(32, 32),  tb, 0, stream>>>(Wo, bcat,                         1024, 1024, 5120, 0);
  wtrans_k<<<dim3(32, 128), tb, 0, stream>>>(W2, bcat,                         4096, 1024, 5120, 1024);

  gemm_fused<<<dim3(28, 16), 512, 0, stream>>>(xn, wqkv1_t, qkb, vtg, acat);
  attn_k<<<dim3(32, 64), 128, 0, stream>>>(qkb, vtg, acat);
  gemm_final<<<dim3(8, 32), 256, 0, stream>>>(acat, bcat, x, dout);
}

// Round 11
// 355.786 us; speedup vs baseline: 1.0439x; 1.0439x over previous
//
#include <hip/hip_runtime.h>

#define DM   1024
#define DFF  4096
#define NH   16
#define HD   64
#define TT   2048
#define BT   4096   // B*T
#define KC   5120   // concat-K: 1024 (attn_o) + 4096 (ff1)

typedef unsigned short u16;
typedef unsigned int   u32;
typedef __attribute__((ext_vector_type(8))) short s16x8;
typedef __attribute__((ext_vector_type(4))) float f32x4;

__device__ __forceinline__ u16 f2bf(float f) {
  u32 u = __builtin_bit_cast(u32, f);
  u += 0x7fffu + ((u >> 16) & 1u);
  return (u16)(u >> 16);
}

// async global->LDS, 16B per lane. HW semantics: dest = wave-uniform base + lane*16.
__device__ __forceinline__ void gl2lds16(const void* g, void* l) {
  __builtin_amdgcn_global_load_lds((__attribute__((address_space(1))) void*)(g),
                                   (__attribute__((address_space(3))) void*)(l),
                                   16, 0, 0);
}

// raw barrier (no vmcnt(0) drain) + scheduler pin
#define S_BARRIER() do { __builtin_amdgcn_s_barrier(); __builtin_amdgcn_sched_barrier(0); } while (0)
#define VMWAIT(n)   asm volatile("s_waitcnt vmcnt(" #n ")" ::: "memory")

// ------- RMSNorm: x fp32 [BT][DM] -> xn bf16 ; also out = x (split-K base) -------
__global__ __launch_bounds__(256) void rmsnorm_k(const float* __restrict__ x,
                                                 const float* __restrict__ w,
                                                 u16* __restrict__ xn,
                                                 float* __restrict__ outx) {
  const int row = blockIdx.x;
  const int t = threadIdx.x;
  const float4 v = ((const float4*)(x + (size_t)row * DM))[t];
  ((float4*)(outx + (size_t)row * DM))[t] = v;   // out = x; gemm_final atomically adds
  float ss = v.x*v.x + v.y*v.y + v.z*v.z + v.w*v.w;
  #pragma unroll
  for (int off = 32; off; off >>= 1) ss += __shfl_xor(ss, off, 64);
  __shared__ float red[4];
  if ((t & 63) == 0) red[t >> 6] = ss;
  __syncthreads();
  const float tot = red[0] + red[1] + red[2] + red[3];
  const float r = __builtin_amdgcn_rsqf(tot * (1.0f / DM) + 1.1920929e-7f);
  const float4 wv = ((const float4*)w)[t];
  u16* o = xn + (size_t)row * DM + t * 4;
  o[0] = f2bf(v.x * r * wv.x);
  o[1] = f2bf(v.y * r * wv.y);
  o[2] = f2bf(v.z * r * wv.z);
  o[3] = f2bf(v.w * r * wv.w);
}

// --- weight transpose+cvt: W fp32 [K][N] -> Wt bf16 [n][pitch] at col-offset koff ---
__global__ __launch_bounds__(256) void wtrans_k(const float* __restrict__ W,
                                                u16* __restrict__ Wt,
                                                int K, int N, int pitch, int koff) {
  __shared__ float tile[32][33];
  const int n0 = blockIdx.x * 32, k0 = blockIdx.y * 32;
  const int tx = threadIdx.x, ty = threadIdx.y;  // (32,8)
  #pragma unroll
  for (int i = 0; i < 4; ++i)
    tile[ty + i*8][tx] = W[(size_t)(k0 + ty + i*8) * N + n0 + tx];
  __syncthreads();
  #pragma unroll
  for (int i = 0; i < 4; ++i)
    Wt[(size_t)(n0 + ty + i*8) * pitch + koff + k0 + tx] = f2bf(tile[tx][ty + i*8]);
}

// ---- fused QKV+FFN1 GEMM: A=xn [4096][1024], Bt [7168][1024] ----
// R3 8-phase schedule (unchanged since; measured ~90 us / 667 TF).
__global__ __launch_bounds__(512, 2) void gemm_fused(const u16* __restrict__ A,
                                                     const u16* __restrict__ Bt,
                                                     u16* __restrict__ qkb,
                                                     u16* __restrict__ vtg,
                                                     u16* __restrict__ acat) {
  const int K = 1024;
  __shared__ u16 sA[2 * 16384];   // 64 KB
  __shared__ u16 sB[2 * 16384];   // 64 KB
  const int t = threadIdx.x;               // 0..511
  const int lane = t & 63, wave = t >> 6;  // 8 waves
  const int quad = lane >> 4, l4 = lane & 15;
  const int wy = wave >> 2, wx = wave & 3; // wave grid 2(M) x 4(N); wave tile 128x64
  const size_t mBase = (size_t)blockIdx.y * 256;
  const size_t nBase = (size_t)blockIdx.x * 256;

  const int grow = t >> 3;                       // 0..63
  const int gchk = ((t & 7) ^ (grow & 7)) * 8;   // pre-swizzled source chunk
  const u16* AgR = A  + (mBase + grow) * K + gchk;
  const u16* BgR = Bt + (nBase + grow) * K + gchk;
  char* dA = (char*)sA;
  char* dB = (char*)sB;
  const int woff = wave * 1024;

  const int cs0 = ((quad)     ^ (l4 & 7)) * 8;   // kk=0
  const int cs1 = ((4 + quad) ^ (l4 & 7)) * 8;   // kk=1

  f32x4 acc[8][4];
  #pragma unroll
  for (int i = 0; i < 8; ++i)
    #pragma unroll
    for (int j = 0; j < 4; ++j)
      acc[i][j] = (f32x4)0.0f;

  s16x8 a[4][2], b[4][2];

  #define STG(p, slot, kt) do {                                                  \
    const int k0_ = (kt) * 64;                                                   \
    if ((p) == 0) {                                                              \
      gl2lds16(BgR + (size_t)0*64*K + k0_, dB + (slot)*32768 +     0 + woff);    \
      gl2lds16(BgR + (size_t)1*64*K + k0_, dB + (slot)*32768 +  8192 + woff);    \
    } else if ((p) == 1) {                                                       \
      gl2lds16(BgR + (size_t)2*64*K + k0_, dB + (slot)*32768 + 16384 + woff);    \
      gl2lds16(BgR + (size_t)3*64*K + k0_, dB + (slot)*32768 + 24576 + woff);    \
    } else if ((p) == 2) {                                                       \
      gl2lds16(AgR + (size_t)0*64*K + k0_, dA + (slot)*32768 +     0 + woff);    \
      gl2lds16(AgR + (size_t)2*64*K + k0_, dA + (slot)*32768 + 16384 + woff);    \
    } else {                                                                     \
      gl2lds16(AgR + (size_t)1*64*K + k0_, dA + (slot)*32768 +  8192 + woff);    \
      gl2lds16(AgR + (size_t)3*64*K + k0_, dA + (slot)*32768 + 24576 + woff);    \
    }                                                                            \
  } while (0)

  #define RDA(slot, qm) do {                                                     \
    const u16* p_ = sA + (slot)*16384 + wy*8192;                                 \
    _Pragma("unroll")                                                            \
    for (int m_ = 0; m_ < 4; ++m_) {                                             \
      const int ro_ = (((qm)*4 + m_)*16 + l4) * 64;                              \
      a[m_][0] = *(const s16x8*)&p_[ro_ + cs0];                                  \
      a[m_][1] = *(const s16x8*)&p_[ro_ + cs1];                                  \
    }                                                                            \
  } while (0)

  #define RDB(slot, qn) do {                                                     \
    const u16* p_ = sB + (slot)*16384 + (wx>>1)*8192 + (wx&1)*4096;              \
    _Pragma("unroll")                                                            \
    for (int n_ = 0; n_ < 2; ++n_) {                                             \
      const int ro_ = (((qn)*2 + n_)*16 + l4) * 64;                              \
      b[(qn)*2 + n_][0] = *(const s16x8*)&p_[ro_ + cs0];                         \
      b[(qn)*2 + n_][1] = *(const s16x8*)&p_[ro_ + cs1];                         \
    }                                                                            \
  } while (0)

  #define MM(qm, qn) do {                                                        \
    __builtin_amdgcn_s_setprio(1);                                               \
    _Pragma("unroll")                                                            \
    for (int m_ = 0; m_ < 4; ++m_)                                               \
      _Pragma("unroll")                                                          \
      for (int n_ = 0; n_ < 2; ++n_) {                                           \
        acc[(qm)*4+m_][(qn)*2+n_] = __builtin_amdgcn_mfma_f32_16x16x32_bf16(     \
            a[m_][0], b[(qn)*2+n_][0], acc[(qm)*4+m_][(qn)*2+n_], 0, 0, 0);      \
        acc[(qm)*4+m_][(qn)*2+n_] = __builtin_amdgcn_mfma_f32_16x16x32_bf16(     \
            a[m_][1], b[(qn)*2+n_][1], acc[(qm)*4+m_][(qn)*2+n_], 0, 0, 0);      \
      }                                                                          \
    __builtin_amdgcn_s_setprio(0);                                               \
  } while (0)

  STG(0, 0, 0); STG(1, 0, 0); STG(2, 0, 0); STG(3, 0, 0);
  VMWAIT(2);
  S_BARRIER();

  for (int i = 0; i < 7; ++i) {
    const int kt1 = 2*i + 1, kt2 = 2*i + 2;
    RDA(0,0); RDB(0,0); STG(0,1,kt1); S_BARRIER(); MM(0,0);            S_BARRIER();
    RDB(0,1);           STG(1,1,kt1); S_BARRIER(); MM(0,1); VMWAIT(4); S_BARRIER();
    RDA(0,1);           STG(2,1,kt1); S_BARRIER(); MM(1,0);            S_BARRIER();
                        STG(3,1,kt1); S_BARRIER(); MM(1,1); VMWAIT(2); S_BARRIER();
    RDA(1,0); RDB(1,0); STG(0,0,kt2); S_BARRIER(); MM(0,0);            S_BARRIER();
    RDB(1,1);           STG(1,0,kt2); S_BARRIER(); MM(0,1); VMWAIT(4); S_BARRIER();
    RDA(1,1);           STG(2,0,kt2); S_BARRIER(); MM(1,0);            S_BARRIER();
                        STG(3,0,kt2); S_BARRIER(); MM(1,1); VMWAIT(2); S_BARRIER();
  }
  RDA(0,0); RDB(0,0); STG(0,1,15); S_BARRIER(); MM(0,0);            S_BARRIER();
  RDB(0,1);           STG(1,1,15); S_BARRIER(); MM(0,1); VMWAIT(4); S_BARRIER();
  RDA(0,1);           STG(2,1,15); S_BARRIER(); MM(1,0);            S_BARRIER();
                      STG(3,1,15); S_BARRIER(); MM(1,1); VMWAIT(2); S_BARRIER();
  RDA(1,0); RDB(1,0);              S_BARRIER(); MM(0,0);            S_BARRIER();
  RDB(1,1);                        S_BARRIER(); MM(0,1); VMWAIT(0); S_BARRIER();
  RDA(1,1);                        S_BARRIER(); MM(1,0);            S_BARRIER();
                                   S_BARRIER(); MM(1,1);            S_BARRIER();

  #undef STG
  #undef RDA
  #undef RDB
  #undef MM

  #pragma unroll
  for (int i = 0; i < 8; ++i) {
    const size_t row0 = mBase + wy*128 + i*16 + quad*4;
    #pragma unroll
    for (int j = 0; j < 4; ++j) {
      const int col = (int)nBase + wx*64 + j*16 + l4;
      if (nBase < 1024) {               // Q: fold (1/sqrt(64))*log2(e)
        #pragma unroll
        for (int rg = 0; rg < 4; ++rg)
          qkb[(row0 + rg) * 2048 + col] = f2bf(acc[i][j][rg] * 0.18033688011f);
      } else if (nBase < 2048) {        // K
        #pragma unroll
        for (int rg = 0; rg < 4; ++rg)
          qkb[(row0 + rg) * 2048 + col] = f2bf(acc[i][j][rg]);
      } else if (nBase < 3072) {        // V: transposed, 4 tokens packed
        const int cv = col - 2048, hh = cv >> 6, dd = cv & 63;
        const int bb = (int)(row0 >> 11), t0 = (int)(row0 & 2047);
        ushort4 pk;
        pk.x = f2bf(acc[i][j][0]); pk.y = f2bf(acc[i][j][1]);
        pk.z = f2bf(acc[i][j][2]); pk.w = f2bf(acc[i][j][3]);
        *(ushort4*)(vtg + ((size_t)((bb*16 + hh)*64 + dd)) * 2048 + t0) = pk;
      } else {                          // FFN1: silu -> A_cat cols 1024..5119
        #pragma unroll
        for (int rg = 0; rg < 4; ++rg) {
          float v = acc[i][j][rg];
          v = v / (1.0f + __expf(-v));
          acat[(row0 + rg) * (size_t)KC + 1024 + (col - 3072)] = f2bf(v);
        }
      }
    }
  }
}

// ---- final GEMM: out += A_cat[4096][5120] * B_cat[1024][5120]^T (out pre-init = x) ----
// R10: SPLIT-K=2. R8/R9 showed final is latency/overlap-bound (LDS only ~40%
// utilized, MfmaUtil 17% both at 2 blocks/CU and 1 block/CU): the thin N=1024
// output gives too few blocks. Split K 5120->2x2560: grid (8,64,2) = 1024 blocks,
// 3-slot ring (36 KB) + launch_bounds(256,4) -> 4 blocks/CU, 16 waves/CU = 4/SIMD
// independent streams. Epilogue: fp32 atomicAdd (device-scope, m20); out=x done
// in rmsnorm_k (stream-ordered). XCD M-chunk swizzle per K-half (512%8==0).
__global__ __launch_bounds__(256, 4) void gemm_final(const u16* __restrict__ A,
                                                     const u16* __restrict__ Bt,
                                                     float* __restrict__ out) {
  __shared__ u16 sA[3 * 64 * 32];    // 12 KB
  __shared__ u16 sB[3 * 128 * 32];   // 24 KB
  const int t = threadIdx.x;
  const int lane = t & 63, wave = t >> 6;
  const int quad = lane >> 4, l4 = lane & 15;
  const int wy = wave >> 1, wx = wave & 1;   // 2x2 wave grid; wave tile 32(M)x64(N)
  const int d  = blockIdx.x + (blockIdx.y << 3);   // 0..511 per K-half
  const int vb = ((d & 7) << 6) | (d >> 3);        // XCD -> 8 contiguous M-panels
  const int bx = vb & 7, by = vb >> 3;
  const size_t mBase = (size_t)by * 64;
  const size_t nBase = (size_t)bx * 128;
  const int kBase = (int)blockIdx.z * 2560;        // split-K half
  const int r  = t >> 2;          // 0..63
  const int c8 = ((t & 3) ^ ((t >> 3) & 3)) * 8;   // pre-swizzled source chunk
  const int qsw = (quad ^ ((l4 >> 1) & 3)) * 8;    // swizzled read offset
  const u16* Ag  = A  + (mBase + r) * KC + kBase + c8;
  const u16* Bg0 = Bt + (nBase + r) * KC + kBase + c8;
  const u16* Bg1 = Bg0 + (size_t)64 * KC;
  char* sAb = (char*)sA + (wave << 10);
  char* sBb = (char*)sB + (wave << 10);

  f32x4 acc[2][4];
  #pragma unroll
  for (int i = 0; i < 2; ++i)
    #pragma unroll
    for (int j = 0; j < 4; ++j)
      acc[i][j] = (f32x4)0.0f;

  auto issue = [&](int sl, int k0) {
    gl2lds16(Ag  + k0, sAb + sl*4096);
    gl2lds16(Bg0 + k0, sBb + sl*8192);
    gl2lds16(Bg1 + k0, sBb + sl*8192 + 4096);
  };

  auto compute = [&](int sl) {
    const u16* pA = sA + sl * 2048;   // u16 elements: 64*32
    const u16* pB = sB + sl * 4096;   // 128*32
    s16x8 af[2], bfr[4];
    #pragma unroll
    for (int i = 0; i < 2; ++i)
      af[i] = *(const s16x8*)&pA[(wy*32 + i*16 + l4) * 32 + qsw];
    #pragma unroll
    for (int j = 0; j < 4; ++j)
      bfr[j] = *(const s16x8*)&pB[(wx*64 + j*16 + l4) * 32 + qsw];
    #pragma unroll
    for (int i = 0; i < 2; ++i)
      #pragma unroll
      for (int j = 0; j < 4; ++j)
        acc[i][j] = __builtin_amdgcn_mfma_f32_16x16x32_bf16(af[i], bfr[j], acc[i][j], 0, 0, 0);
  };

  const int NIT = 2560 / 32;   // 80 per K-half
  issue(0, 0); issue(1, 32);
  for (int kt = 0; kt < NIT - 2; ++kt) {
    VMWAIT(3);                    // my 3 loads for tile kt landed (kt+1's in flight)
    S_BARRIER();                  // all waves' tile-kt loads landed; kt-1 reads done
    issue((kt + 2) % 3, (kt + 2) * 32);   // slot of kt-1, freed by this barrier
    compute(kt % 3);
  }
  VMWAIT(3); S_BARRIER(); compute((NIT - 2) % 3);
  VMWAIT(0); S_BARRIER(); compute((NIT - 1) % 3);

  #pragma unroll
  for (int i = 0; i < 2; ++i) {
    const size_t row0 = mBase + wy*32 + i*16 + quad*4;
    #pragma unroll
    for (int j = 0; j < 4; ++j) {
      const int col = (int)nBase + wx*64 + j*16 + l4;
      #pragma unroll
      for (int rg = 0; rg < 4; ++rg)
        atomicAdd(out + (row0 + rg) * (size_t)DM + col, acc[i][j][rg]);
    }
  }
}

// ------- causal flash attention, fixed-max, in-block split-K=2 over waves -------
// writes bf16 into A_cat cols 0..1023 (pitch 5120)
__global__ __launch_bounds__(128) void attn_k(const u16* __restrict__ qk,
                                              const u16* __restrict__ vtg,
                                              u16* __restrict__ acat) {
  const int bh = blockIdx.x, b = bh >> 4, h = bh & 15;
  const int qt = 63 - blockIdx.y;
  const int qw = qt * 32;
  const int wave = threadIdx.x >> 6, lane = threadIdx.x & 63;
  const int quad = lane >> 4, l4 = lane & 15;
  const u16* Qp = qk + (size_t)b * TT * 2048 + h * HD;
  const u16* Kp = Qp + 1024;
  const u16* Vp = vtg + (size_t)bh * 64 * 2048;

  __shared__ u16 Pb[2][32][72];
  __shared__ float Ob[32][68];
  __shared__ float Lb[32];

  s16x8 qf[2][2];
  #pragma unroll
  for (int mi = 0; mi < 2; ++mi)
    #pragma unroll
    for (int kf = 0; kf < 2; ++kf)
      qf[mi][kf] = *(const s16x8*)(Qp + (size_t)(qw + mi*16 + l4) * 2048 + kf*32 + quad*8);

  const s16x8 ones = {0x3F80,0x3F80,0x3F80,0x3F80,0x3F80,0x3F80,0x3F80,0x3F80};

  f32x4 o[2][4];
  f32x4 lacc[2];
  #pragma unroll
  for (int mi = 0; mi < 2; ++mi) {
    lacc[mi] = (f32x4)0.0f;
    #pragma unroll
    for (int ni = 0; ni < 4; ++ni) o[mi][ni] = (f32x4)0.0f;
  }

  const int n   = (qt + 2) >> 1;
  const int n0  = (n + 1) >> 1;
  const int kt0 = wave ? n0 : 0;
  const int kt1 = wave ? n : n0;

  for (int kt = kt0; kt < kt1; ++kt) {
    const int k0 = kt * 64;

    f32x4 st[4][2];
    #pragma unroll
    for (int nj = 0; nj < 4; ++nj) {
      const u16* kr = Kp + (size_t)(k0 + nj*16 + l4) * 2048 + quad*8;
      const s16x8 kf0 = *(const s16x8*)kr;
      const s16x8 kf1 = *(const s16x8*)(kr + 32);
      #pragma unroll
      for (int mi = 0; mi < 2; ++mi) {
        f32x4 a = (f32x4)0.0f;
        a = __builtin_amdgcn_mfma_f32_16x16x32_bf16(kf0, qf[mi][0], a, 0, 0, 0);
        a = __builtin_amdgcn_mfma_f32_16x16x32_bf16(kf1, qf[mi][1], a, 0, 0, 0);
        st[nj][mi] = a;
      }
    }

    s16x8 vb[2][4];
    #pragma unroll
    for (int kf2 = 0; kf2 < 2; ++kf2)
      #pragma unroll
      for (int ni = 0; ni < 4; ++ni)
        vb[kf2][ni] = *(const s16x8*)(Vp + (size_t)(ni*16 + l4) * 2048 + k0 + kf2*32 + quad*8);

    if (k0 + 63 > qw) {
      #pragma unroll
      for (int nj = 0; nj < 4; ++nj)
        #pragma unroll
        for (int mi = 0; mi < 2; ++mi)
          #pragma unroll
          for (int rg = 0; rg < 4; ++rg) {
            const int key = k0 + nj*16 + quad*4 + rg;
            const int q   = qw + mi*16 + l4;
            if (key > q) st[nj][mi][rg] = -1e30f;
          }
    }

    #pragma unroll
    for (int nj = 0; nj < 4; ++nj)
      #pragma unroll
      for (int mi = 0; mi < 2; ++mi) {
        float p0 = __builtin_amdgcn_exp2f(st[nj][mi][0]);
        float p1 = __builtin_amdgcn_exp2f(st[nj][mi][1]);
        float p2 = __builtin_amdgcn_exp2f(st[nj][mi][2]);
        float p3 = __builtin_amdgcn_exp2f(st[nj][mi][3]);
        uint2 w;
        w.x = __builtin_amdgcn_perm(__builtin_bit_cast(u32, p1),
                                    __builtin_bit_cast(u32, p0), 0x07060302u);
        w.y = __builtin_amdgcn_perm(__builtin_bit_cast(u32, p3),
                                    __builtin_bit_cast(u32, p2), 0x07060302u);
        *(uint2*)&Pb[wave][mi*16 + l4][nj*16 + quad*4] = w;
      }

    #pragma unroll
    for (int kf2 = 0; kf2 < 2; ++kf2) {
      s16x8 pa[2];
      #pragma unroll
      for (int mi = 0; mi < 2; ++mi)
        pa[mi] = *(const s16x8*)&Pb[wave][mi*16 + l4][kf2*32 + quad*8];
      #pragma unroll
      for (int mi = 0; mi < 2; ++mi) {
        lacc[mi] = __builtin_amdgcn_mfma_f32_16x16x32_bf16(pa[mi], ones, lacc[mi], 0, 0, 0);
        #pragma unroll
        for (int ni = 0; ni < 4; ++ni)
          o[mi][ni] = __builtin_amdgcn_mfma_f32_16x16x32_bf16(pa[mi], vb[kf2][ni], o[mi][ni], 0, 0, 0);
      }
    }
  }

  if (wave == 1) {
    #pragma unroll
    for (int mi = 0; mi < 2; ++mi)
      #pragma unroll
      for (int rg = 0; rg < 4; ++rg) {
        const int row = mi*16 + quad*4 + rg;
        #pragma unroll
        for (int ni = 0; ni < 4; ++ni) Ob[row][ni*16 + l4] = o[mi][ni][rg];
        if (l4 == 0) Lb[row] = lacc[mi][rg];
      }
  }
  __syncthreads();
  if (wave == 0) {
    #pragma unroll
    for (int mi = 0; mi < 2; ++mi)
      #pragma unroll
      for (int rg = 0; rg < 4; ++rg) {
        const int row = mi*16 + quad*4 + rg;
        const float inv = 1.0f / (lacc[mi][rg] + Lb[row]);
        #pragma unroll
        for (int ni = 0; ni < 4; ++ni)
          Pb[0][row][ni*16 + l4] = f2bf((o[mi][ni][rg] + Ob[row][ni*16 + l4]) * inv);
      }
    #pragma unroll
    for (int it = 0; it < 4; ++it) {
      const int row = it*8 + (lane >> 3);
      const int c0  = (lane & 7) * 8;
      const s16x8 pk = *(const s16x8*)&Pb[0][row][c0];
      *(s16x8*)(acat + ((size_t)b * TT + qw + row) * KC + h*HD + c0) = pk;
    }
  }
}

extern "C" void kernel_launch(void* const* d_in, const int* in_sizes, int n_in,
                              void* d_out, int out_size, void* d_ws, size_t ws_size,
                              hipStream_t stream) {
  (void)in_sizes; (void)n_in; (void)out_size; (void)ws_size;
  const float* x  = (const float*)d_in[0];
  const float* nw = (const float*)d_in[1];
  const float* Wq = (const float*)d_in[2];
  const float* Wk = (const float*)d_in[3];
  const float* Wv = (const float*)d_in[4];
  const float* Wo = (const float*)d_in[5];
  const float* W1 = (const float*)d_in[6];
  const float* W2 = (const float*)d_in[7];

  char* ws = (char*)d_ws;
  u16*   xn      = (u16*)(ws);                          //  8 MB  [4096][1024]
  u16*   wqkv1_t = (u16*)(ws + ((size_t)8  << 20));     // 14 MB  [7168][1024] Wq|Wk|Wv|W1 ^T
  u16*   bcat    = (u16*)(ws + ((size_t)22 << 20));     // 10 MB  [1024][5120] Wo^T|W2^T
  u16*   qkb     = (u16*)(ws + ((size_t)32 << 20));     // 16 MB  [4096][2048] (q|k)
  u16*   vtg     = (u16*)(ws + ((size_t)48 << 20));     //  8 MB  [32][64][2048] V^T
  u16*   acat    = (u16*)(ws + ((size_t)56 << 20));     // 40 MB  [4096][5120] attn_o|ff1
  float* dout    = (float*)d_out;                       // 16 MB  [4096][1024] fp32

  rmsnorm_k<<<BT, 256, 0, stream>>>(x, nw, xn, dout);
  const dim3 tb(32, 8);
  wtrans_k<<<dim3(32, 32),  tb, 0, stream>>>(Wq, wqkv1_t,                      1024, 1024, 1024, 0);
  wtrans_k<<<dim3(32, 32),  tb, 0, stream>>>(Wk, wqkv1_t + (size_t)1024*1024,  1024, 1024, 1024, 0);
  wtrans_k<<<dim3(32, 32),  tb, 0, stream>>>(Wv, wqkv1_t + (size_t)2048*1024,  1024, 1024, 1024, 0);
  wtrans_k<<<dim3(128, 32), tb, 0, stream>>>(W1, wqkv1_t + (size_t)3072*1024,  1024, 4096, 1024, 0);
  wtrans_k<<<dim3(32, 32),  tb, 0, stream>>>(Wo, bcat,                         1024, 1024, 5120, 0);
  wtrans_k<<<dim3(32, 128), tb, 0, stream>>>(W2, bcat,                         4096, 1024, 5120, 1024);

  gemm_fused<<<dim3(28, 16), 512, 0, stream>>>(xn, wqkv1_t, qkb, vtg, acat);
  attn_k<<<dim3(32, 64), 128, 0, stream>>>(qkb, vtg, acat);
  gemm_final<<<dim3(8, 64, 2), 256, 0, stream>>>(acat, bcat, dout);
}

// Round 13
// 351.958 us; speedup vs baseline: 1.0552x; 1.0109x over previous
//
#include <hip/hip_runtime.h>

#define DM   1024
#define DFF  4096
#define NH   16
#define HD   64
#define TT   2048
#define BT   4096   // B*T
#define KC   5120   // concat-K: 1024 (attn_o) + 4096 (ff1)

typedef unsigned short u16;
typedef unsigned int   u32;
typedef __attribute__((ext_vector_type(8))) short s16x8;
typedef __attribute__((ext_vector_type(4))) float f32x4;

__device__ __forceinline__ u16 f2bf(float f) {
  u32 u = __builtin_bit_cast(u32, f);
  u += 0x7fffu + ((u >> 16) & 1u);
  return (u16)(u >> 16);
}

// async global->LDS, 16B per lane. HW semantics: dest = wave-uniform base + lane*16.
__device__ __forceinline__ void gl2lds16(const void* g, void* l) {
  __builtin_amdgcn_global_load_lds((__attribute__((address_space(1))) void*)(g),
                                   (__attribute__((address_space(3))) void*)(l),
                                   16, 0, 0);
}

// raw barrier (no vmcnt(0) drain) + scheduler pin
#define S_BARRIER() do { __builtin_amdgcn_s_barrier(); __builtin_amdgcn_sched_barrier(0); } while (0)
#define VMWAIT(n)   asm volatile("s_waitcnt vmcnt(" #n ")" ::: "memory")

// ------- RMSNorm: x fp32 [BT][DM] -> xn bf16 ; also out = x (split-K base) -------
__global__ __launch_bounds__(256) void rmsnorm_k(const float* __restrict__ x,
                                                 const float* __restrict__ w,
                                                 u16* __restrict__ xn,
                                                 float* __restrict__ outx) {
  const int row = blockIdx.x;
  const int t = threadIdx.x;
  const float4 v = ((const float4*)(x + (size_t)row * DM))[t];
  ((float4*)(outx + (size_t)row * DM))[t] = v;   // out = x; gemm_final atomically adds
  float ss = v.x*v.x + v.y*v.y + v.z*v.z + v.w*v.w;
  #pragma unroll
  for (int off = 32; off; off >>= 1) ss += __shfl_xor(ss, off, 64);
  __shared__ float red[4];
  if ((t & 63) == 0) red[t >> 6] = ss;
  __syncthreads();
  const float tot = red[0] + red[1] + red[2] + red[3];
  const float r = __builtin_amdgcn_rsqf(tot * (1.0f / DM) + 1.1920929e-7f);
  const float4 wv = ((const float4*)w)[t];
  u16* o = xn + (size_t)row * DM + t * 4;
  o[0] = f2bf(v.x * r * wv.x);
  o[1] = f2bf(v.y * r * wv.y);
  o[2] = f2bf(v.z * r * wv.z);
  o[3] = f2bf(v.w * r * wv.w);
}

// --- weight transpose+cvt: W fp32 [K][N] -> Wt bf16 [n][pitch] at col-offset koff ---
__global__ __launch_bounds__(256) void wtrans_k(const float* __restrict__ W,
                                                u16* __restrict__ Wt,
                                                int K, int N, int pitch, int koff) {
  __shared__ float tile[32][33];
  const int n0 = blockIdx.x * 32, k0 = blockIdx.y * 32;
  const int tx = threadIdx.x, ty = threadIdx.y;  // (32,8)
  #pragma unroll
  for (int i = 0; i < 4; ++i)
    tile[ty + i*8][tx] = W[(size_t)(k0 + ty + i*8) * N + n0 + tx];
  __syncthreads();
  #pragma unroll
  for (int i = 0; i < 4; ++i)
    Wt[(size_t)(n0 + ty + i*8) * pitch + koff + k0 + tx] = f2bf(tile[tx][ty + i*8]);
}

// ---- fused QKV+FFN1 GEMM: A=xn [4096][1024], Bt [7168][1024] ----
// R3 8-phase schedule (unchanged since; measured ~92 us / 654 TF).
__global__ __launch_bounds__(512, 2) void gemm_fused(const u16* __restrict__ A,
                                                     const u16* __restrict__ Bt,
                                                     u16* __restrict__ qkb,
                                                     u16* __restrict__ vtg,
                                                     u16* __restrict__ acat) {
  const int K = 1024;
  __shared__ u16 sA[2 * 16384];   // 64 KB
  __shared__ u16 sB[2 * 16384];   // 64 KB
  const int t = threadIdx.x;               // 0..511
  const int lane = t & 63, wave = t >> 6;  // 8 waves
  const int quad = lane >> 4, l4 = lane & 15;
  const int wy = wave >> 2, wx = wave & 3; // wave grid 2(M) x 4(N); wave tile 128x64
  const size_t mBase = (size_t)blockIdx.y * 256;
  const size_t nBase = (size_t)blockIdx.x * 256;

  const int grow = t >> 3;                       // 0..63
  const int gchk = ((t & 7) ^ (grow & 7)) * 8;   // pre-swizzled source chunk
  const u16* AgR = A  + (mBase + grow) * K + gchk;
  const u16* BgR = Bt + (nBase + grow) * K + gchk;
  char* dA = (char*)sA;
  char* dB = (char*)sB;
  const int woff = wave * 1024;

  const int cs0 = ((quad)     ^ (l4 & 7)) * 8;   // kk=0
  const int cs1 = ((4 + quad) ^ (l4 & 7)) * 8;   // kk=1

  f32x4 acc[8][4];
  #pragma unroll
  for (int i = 0; i < 8; ++i)
    #pragma unroll
    for (int j = 0; j < 4; ++j)
      acc[i][j] = (f32x4)0.0f;

  s16x8 a[4][2], b[4][2];

  #define STG(p, slot, kt) do {                                                  \
    const int k0_ = (kt) * 64;                                                   \
    if ((p) == 0) {                                                              \
      gl2lds16(BgR + (size_t)0*64*K + k0_, dB + (slot)*32768 +     0 + woff);    \
      gl2lds16(BgR + (size_t)1*64*K + k0_, dB + (slot)*32768 +  8192 + woff);    \
    } else if ((p) == 1) {                                                       \
      gl2lds16(BgR + (size_t)2*64*K + k0_, dB + (slot)*32768 + 16384 + woff);    \
      gl2lds16(BgR + (size_t)3*64*K + k0_, dB + (slot)*32768 + 24576 + woff);    \
    } else if ((p) == 2) {                                                       \
      gl2lds16(AgR + (size_t)0*64*K + k0_, dA + (slot)*32768 +     0 + woff);    \
      gl2lds16(AgR + (size_t)2*64*K + k0_, dA + (slot)*32768 + 16384 + woff);    \
    } else {                                                                     \
      gl2lds16(AgR + (size_t)1*64*K + k0_, dA + (slot)*32768 +  8192 + woff);    \
      gl2lds16(AgR + (size_t)3*64*K + k0_, dA + (slot)*32768 + 24576 + woff);    \
    }                                                                            \
  } while (0)

  #define RDA(slot, qm) do {                                                     \
    const u16* p_ = sA + (slot)*16384 + wy*8192;                                 \
    _Pragma("unroll")                                                            \
    for (int m_ = 0; m_ < 4; ++m_) {                                             \
      const int ro_ = (((qm)*4 + m_)*16 + l4) * 64;                              \
      a[m_][0] = *(const s16x8*)&p_[ro_ + cs0];                                  \
      a[m_][1] = *(const s16x8*)&p_[ro_ + cs1];                                  \
    }                                                                            \
  } while (0)

  #define RDB(slot, qn) do {                                                     \
    const u16* p_ = sB + (slot)*16384 + (wx>>1)*8192 + (wx&1)*4096;              \
    _Pragma("unroll")                                                            \
    for (int n_ = 0; n_ < 2; ++n_) {                                             \
      const int ro_ = (((qn)*2 + n_)*16 + l4) * 64;                              \
      b[(qn)*2 + n_][0] = *(const s16x8*)&p_[ro_ + cs0];                         \
      b[(qn)*2 + n_][1] = *(const s16x8*)&p_[ro_ + cs1];                         \
    }                                                                            \
  } while (0)

  #define MM(qm, qn) do {                                                        \
    __builtin_amdgcn_s_setprio(1);                                               \
    _Pragma("unroll")                                                            \
    for (int m_ = 0; m_ < 4; ++m_)                                               \
      _Pragma("unroll")                                                          \
      for (int n_ = 0; n_ < 2; ++n_) {                                           \
        acc[(qm)*4+m_][(qn)*2+n_] = __builtin_amdgcn_mfma_f32_16x16x32_bf16(     \
            a[m_][0], b[(qn)*2+n_][0], acc[(qm)*4+m_][(qn)*2+n_], 0, 0, 0);      \
        acc[(qm)*4+m_][(qn)*2+n_] = __builtin_amdgcn_mfma_f32_16x16x32_bf16(     \
            a[m_][1], b[(qn)*2+n_][1], acc[(qm)*4+m_][(qn)*2+n_], 0, 0, 0);      \
      }                                                                          \
    __builtin_amdgcn_s_setprio(0);                                               \
  } while (0)

  STG(0, 0, 0); STG(1, 0, 0); STG(2, 0, 0); STG(3, 0, 0);
  VMWAIT(2);
  S_BARRIER();

  for (int i = 0; i < 7; ++i) {
    const int kt1 = 2*i + 1, kt2 = 2*i + 2;
    RDA(0,0); RDB(0,0); STG(0,1,kt1); S_BARRIER(); MM(0,0);            S_BARRIER();
    RDB(0,1);           STG(1,1,kt1); S_BARRIER(); MM(0,1); VMWAIT(4); S_BARRIER();
    RDA(0,1);           STG(2,1,kt1); S_BARRIER(); MM(1,0);            S_BARRIER();
                        STG(3,1,kt1); S_BARRIER(); MM(1,1); VMWAIT(2); S_BARRIER();
    RDA(1,0); RDB(1,0); STG(0,0,kt2); S_BARRIER(); MM(0,0);            S_BARRIER();
    RDB(1,1);           STG(1,0,kt2); S_BARRIER(); MM(0,1); VMWAIT(4); S_BARRIER();
    RDA(1,1);           STG(2,0,kt2); S_BARRIER(); MM(1,0);            S_BARRIER();
                        STG(3,0,kt2); S_BARRIER(); MM(1,1); VMWAIT(2); S_BARRIER();
  }
  RDA(0,0); RDB(0,0); STG(0,1,15); S_BARRIER(); MM(0,0);            S_BARRIER();
  RDB(0,1);           STG(1,1,15); S_BARRIER(); MM(0,1); VMWAIT(4); S_BARRIER();
  RDA(0,1);           STG(2,1,15); S_BARRIER(); MM(1,0);            S_BARRIER();
                      STG(3,1,15); S_BARRIER(); MM(1,1); VMWAIT(2); S_BARRIER();
  RDA(1,0); RDB(1,0);              S_BARRIER(); MM(0,0);            S_BARRIER();
  RDB(1,1);                        S_BARRIER(); MM(0,1); VMWAIT(0); S_BARRIER();
  RDA(1,1);                        S_BARRIER(); MM(1,0);            S_BARRIER();
                                   S_BARRIER(); MM(1,1);            S_BARRIER();

  #undef STG
  #undef RDA
  #undef RDB
  #undef MM

  #pragma unroll
  for (int i = 0; i < 8; ++i) {
    const size_t row0 = mBase + wy*128 + i*16 + quad*4;
    #pragma unroll
    for (int j = 0; j < 4; ++j) {
      const int col = (int)nBase + wx*64 + j*16 + l4;
      if (nBase < 1024) {               // Q: fold (1/sqrt(64))*log2(e)
        #pragma unroll
        for (int rg = 0; rg < 4; ++rg)
          qkb[(row0 + rg) * 2048 + col] = f2bf(acc[i][j][rg] * 0.18033688011f);
      } else if (nBase < 2048) {        // K
        #pragma unroll
        for (int rg = 0; rg < 4; ++rg)
          qkb[(row0 + rg) * 2048 + col] = f2bf(acc[i][j][rg]);
      } else if (nBase < 3072) {        // V: transposed, 4 tokens packed
        const int cv = col - 2048, hh = cv >> 6, dd = cv & 63;
        const int bb = (int)(row0 >> 11), t0 = (int)(row0 & 2047);
        ushort4 pk;
        pk.x = f2bf(acc[i][j][0]); pk.y = f2bf(acc[i][j][1]);
        pk.z = f2bf(acc[i][j][2]); pk.w = f2bf(acc[i][j][3]);
        *(ushort4*)(vtg + ((size_t)((bb*16 + hh)*64 + dd)) * 2048 + t0) = pk;
      } else {                          // FFN1: silu -> A_cat cols 1024..5119
        #pragma unroll
        for (int rg = 0; rg < 4; ++rg) {
          float v = acc[i][j][rg];
          v = v / (1.0f + __expf(-v));
          acat[(row0 + rg) * (size_t)KC + 1024 + (col - 3072)] = f2bf(v);
        }
      }
    }
  }
}

// ---- final GEMM: out += A_cat[4096][5120] * B_cat[1024][5120]^T (out pre-init = x) ----
// R10 split-K=2 (measured WIN in R11: 95 -> ~83 us, dropped out of top-5).
__global__ __launch_bounds__(256, 4) void gemm_final(const u16* __restrict__ A,
                                                     const u16* __restrict__ Bt,
                                                     float* __restrict__ out) {
  __shared__ u16 sA[3 * 64 * 32];    // 12 KB
  __shared__ u16 sB[3 * 128 * 32];   // 24 KB
  const int t = threadIdx.x;
  const int lane = t & 63, wave = t >> 6;
  const int quad = lane >> 4, l4 = lane & 15;
  const int wy = wave >> 1, wx = wave & 1;   // 2x2 wave grid; wave tile 32(M)x64(N)
  const int d  = blockIdx.x + (blockIdx.y << 3);   // 0..511 per K-half
  const int vb = ((d & 7) << 6) | (d >> 3);        // XCD -> 8 contiguous M-panels
  const int bx = vb & 7, by = vb >> 3;
  const size_t mBase = (size_t)by * 64;
  const size_t nBase = (size_t)bx * 128;
  const int kBase = (int)blockIdx.z * 2560;        // split-K half
  const int r  = t >> 2;          // 0..63
  const int c8 = ((t & 3) ^ ((t >> 3) & 3)) * 8;   // pre-swizzled source chunk
  const int qsw = (quad ^ ((l4 >> 1) & 3)) * 8;    // swizzled read offset
  const u16* Ag  = A  + (mBase + r) * KC + kBase + c8;
  const u16* Bg0 = Bt + (nBase + r) * KC + kBase + c8;
  const u16* Bg1 = Bg0 + (size_t)64 * KC;
  char* sAb = (char*)sA + (wave << 10);
  char* sBb = (char*)sB + (wave << 10);

  f32x4 acc[2][4];
  #pragma unroll
  for (int i = 0; i < 2; ++i)
    #pragma unroll
    for (int j = 0; j < 4; ++j)
      acc[i][j] = (f32x4)0.0f;

  auto issue = [&](int sl, int k0) {
    gl2lds16(Ag  + k0, sAb + sl*4096);
    gl2lds16(Bg0 + k0, sBb + sl*8192);
    gl2lds16(Bg1 + k0, sBb + sl*8192 + 4096);
  };

  auto compute = [&](int sl) {
    const u16* pA = sA + sl * 2048;   // u16 elements: 64*32
    const u16* pB = sB + sl * 4096;   // 128*32
    s16x8 af[2], bfr[4];
    #pragma unroll
    for (int i = 0; i < 2; ++i)
      af[i] = *(const s16x8*)&pA[(wy*32 + i*16 + l4) * 32 + qsw];
    #pragma unroll
    for (int j = 0; j < 4; ++j)
      bfr[j] = *(const s16x8*)&pB[(wx*64 + j*16 + l4) * 32 + qsw];
    #pragma unroll
    for (int i = 0; i < 2; ++i)
      #pragma unroll
      for (int j = 0; j < 4; ++j)
        acc[i][j] = __builtin_amdgcn_mfma_f32_16x16x32_bf16(af[i], bfr[j], acc[i][j], 0, 0, 0);
  };

  const int NIT = 2560 / 32;   // 80 per K-half
  issue(0, 0); issue(1, 32);
  for (int kt = 0; kt < NIT - 2; ++kt) {
    VMWAIT(3);                    // my 3 loads for tile kt landed (kt+1's in flight)
    S_BARRIER();                  // all waves' tile-kt loads landed; kt-1 reads done
    issue((kt + 2) % 3, (kt + 2) * 32);   // slot of kt-1, freed by this barrier
    compute(kt % 3);
  }
  VMWAIT(3); S_BARRIER(); compute((NIT - 2) % 3);
  VMWAIT(0); S_BARRIER(); compute((NIT - 1) % 3);

  #pragma unroll
  for (int i = 0; i < 2; ++i) {
    const size_t row0 = mBase + wy*32 + i*16 + quad*4;
    #pragma unroll
    for (int j = 0; j < 4; ++j) {
      const int col = (int)nBase + wx*64 + j*16 + l4;
      #pragma unroll
      for (int rg = 0; rg < 4; ++rg)
        atomicAdd(out + (row0 + rg) * (size_t)DM + col, acc[i][j][rg]);
    }
  }
}

// ------- causal flash attention, fixed-max, in-block split-K=2 over waves -------
// R12: software pipeline. K-frags for tile kt+1 prefetched into the alternate
// register set (kfA/kfB, statically indexed via duplicated loop body — rule 20)
// while tile kt computes; V issue moved BEFORE the QK MFMAs. Theory: attn is
// L2/L3-latency-exposed (K loads fed MFMA immediately; 16 cache lines per
// strided load inst; only 2-4 waves/SIMD of TLP). Math unchanged.
// writes bf16 into A_cat cols 0..1023 (pitch 5120)
__global__ __launch_bounds__(128) void attn_k(const u16* __restrict__ qk,
                                              const u16* __restrict__ vtg,
                                              u16* __restrict__ acat) {
  const int bh = blockIdx.x, b = bh >> 4, h = bh & 15;
  const int qt = 63 - blockIdx.y;
  const int qw = qt * 32;
  const int wave = threadIdx.x >> 6, lane = threadIdx.x & 63;
  const int quad = lane >> 4, l4 = lane & 15;
  const u16* Qp = qk + (size_t)b * TT * 2048 + h * HD;
  const u16* Kp = Qp + 1024;
  const u16* Vp = vtg + (size_t)bh * 64 * 2048;

  __shared__ u16 Pb[2][32][72];
  __shared__ float Ob[32][68];
  __shared__ float Lb[32];

  s16x8 qf[2][2];
  #pragma unroll
  for (int mi = 0; mi < 2; ++mi)
    #pragma unroll
    for (int kf = 0; kf < 2; ++kf)
      qf[mi][kf] = *(const s16x8*)(Qp + (size_t)(qw + mi*16 + l4) * 2048 + kf*32 + quad*8);

  const s16x8 ones = {0x3F80,0x3F80,0x3F80,0x3F80,0x3F80,0x3F80,0x3F80,0x3F80};

  f32x4 o[2][4];
  f32x4 lacc[2];
  #pragma unroll
  for (int mi = 0; mi < 2; ++mi) {
    lacc[mi] = (f32x4)0.0f;
    #pragma unroll
    for (int ni = 0; ni < 4; ++ni) o[mi][ni] = (f32x4)0.0f;
  }

  const int n   = (qt + 2) >> 1;
  const int n0  = (n + 1) >> 1;
  const int kt0 = wave ? n0 : 0;
  const int kt1 = wave ? n : n0;

  // load 8 K-fragments of tile ktv into register array KF
  #define LOADK(KF, ktv) do {                                                    \
    const int kk0_ = (ktv) * 64;                                                 \
    _Pragma("unroll")                                                            \
    for (int nj_ = 0; nj_ < 4; ++nj_) {                                          \
      const u16* kr_ = Kp + (size_t)(kk0_ + nj_*16 + l4) * 2048 + quad*8;        \
      KF[nj_*2]     = *(const s16x8*)kr_;                                        \
      KF[nj_*2 + 1] = *(const s16x8*)(kr_ + 32);                                 \
    }                                                                            \
  } while (0)

  // full k-tile body using K-fragments in KF
  #define KBODY(KF, ktv) do {                                                    \
    const int k0 = (ktv) * 64;                                                   \
    s16x8 vb[2][4];                                                              \
    _Pragma("unroll")                                                            \
    for (int kf2 = 0; kf2 < 2; ++kf2)                                            \
      _Pragma("unroll")                                                          \
      for (int ni = 0; ni < 4; ++ni)                                             \
        vb[kf2][ni] = *(const s16x8*)(Vp + (size_t)(ni*16 + l4) * 2048 + k0 + kf2*32 + quad*8); \
    f32x4 st[4][2];                                                              \
    _Pragma("unroll")                                                            \
    for (int nj = 0; nj < 4; ++nj)                                               \
      _Pragma("unroll")                                                          \
      for (int mi = 0; mi < 2; ++mi) {                                           \
        f32x4 aa = (f32x4)0.0f;                                                  \
        aa = __builtin_amdgcn_mfma_f32_16x16x32_bf16(KF[nj*2],   qf[mi][0], aa, 0, 0, 0); \
        aa = __builtin_amdgcn_mfma_f32_16x16x32_bf16(KF[nj*2+1], qf[mi][1], aa, 0, 0, 0); \
        st[nj][mi] = aa;                                                         \
      }                                                                          \
    if (k0 + 63 > qw) {                                                          \
      _Pragma("unroll")                                                          \
      for (int nj = 0; nj < 4; ++nj)                                             \
        _Pragma("unroll")                                                        \
        for (int mi = 0; mi < 2; ++mi)                                           \
          _Pragma("unroll")                                                      \
          for (int rg = 0; rg < 4; ++rg) {                                       \
            const int key = k0 + nj*16 + quad*4 + rg;                            \
            const int q   = qw + mi*16 + l4;                                     \
            if (key > q) st[nj][mi][rg] = -1e30f;                                \
          }                                                                      \
    }                                                                            \
    _Pragma("unroll")                                                            \
    for (int nj = 0; nj < 4; ++nj)                                               \
      _Pragma("unroll")                                                          \
      for (int mi = 0; mi < 2; ++mi) {                                           \
        float p0 = __builtin_amdgcn_exp2f(st[nj][mi][0]);                        \
        float p1 = __builtin_amdgcn_exp2f(st[nj][mi][1]);                        \
        float p2 = __builtin_amdgcn_exp2f(st[nj][mi][2]);                        \
        float p3 = __builtin_amdgcn_exp2f(st[nj][mi][3]);                        \
        uint2 w;                                                                 \
        w.x = __builtin_amdgcn_perm(__builtin_bit_cast(u32, p1),                 \
                                    __builtin_bit_cast(u32, p0), 0x07060302u);   \
        w.y = __builtin_amdgcn_perm(__builtin_bit_cast(u32, p3),                 \
                                    __builtin_bit_cast(u32, p2), 0x07060302u);   \
        *(uint2*)&Pb[wave][mi*16 + l4][nj*16 + quad*4] = w;                      \
      }                                                                          \
    _Pragma("unroll")                                                            \
    for (int kf2 = 0; kf2 < 2; ++kf2) {                                          \
      s16x8 pa[2];                                                               \
      _Pragma("unroll")                                                          \
      for (int mi = 0; mi < 2; ++mi)                                             \
        pa[mi] = *(const s16x8*)&Pb[wave][mi*16 + l4][kf2*32 + quad*8];          \
      _Pragma("unroll")                                                          \
      for (int mi = 0; mi < 2; ++mi) {                                           \
        lacc[mi] = __builtin_amdgcn_mfma_f32_16x16x32_bf16(pa[mi], ones, lacc[mi], 0, 0, 0); \
        _Pragma("unroll")                                                        \
        for (int ni = 0; ni < 4; ++ni)                                           \
          o[mi][ni] = __builtin_amdgcn_mfma_f32_16x16x32_bf16(pa[mi], vb[kf2][ni], o[mi][ni], 0, 0, 0); \
      }                                                                          \
    }                                                                            \
  } while (0)

  if (kt0 < kt1) {
    s16x8 kfA[8], kfB[8];
    LOADK(kfA, kt0);
    int kt = kt0;
    for (;;) {
      if (kt + 1 < kt1) LOADK(kfB, kt + 1);   // prefetch next tile's K
      KBODY(kfA, kt);
      ++kt;
      if (kt >= kt1) break;
      if (kt + 1 < kt1) LOADK(kfA, kt + 1);
      KBODY(kfB, kt);
      ++kt;
      if (kt >= kt1) break;
    }
  }

  #undef LOADK
  #undef KBODY

  if (wave == 1) {
    #pragma unroll
    for (int mi = 0; mi < 2; ++mi)
      #pragma unroll
      for (int rg = 0; rg < 4; ++rg) {
        const int row = mi*16 + quad*4 + rg;
        #pragma unroll
        for (int ni = 0; ni < 4; ++ni) Ob[row][ni*16 + l4] = o[mi][ni][rg];
        if (l4 == 0) Lb[row] = lacc[mi][rg];
      }
  }
  __syncthreads();
  if (wave == 0) {
    #pragma unroll
    for (int mi = 0; mi < 2; ++mi)
      #pragma unroll
      for (int rg = 0; rg < 4; ++rg) {
        const int row = mi*16 + quad*4 + rg;
        const float inv = 1.0f / (lacc[mi][rg] + Lb[row]);
        #pragma unroll
        for (int ni = 0; ni < 4; ++ni)
          Pb[0][row][ni*16 + l4] = f2bf((o[mi][ni][rg] + Ob[row][ni*16 + l4]) * inv);
      }
    #pragma unroll
    for (int it = 0; it < 4; ++it) {
      const int row = it*8 + (lane >> 3);
      const int c0  = (lane & 7) * 8;
      const s16x8 pk = *(const s16x8*)&Pb[0][row][c0];
      *(s16x8*)(acat + ((size_t)b * TT + qw + row) * KC + h*HD + c0) = pk;
    }
  }
}

extern "C" void kernel_launch(void* const* d_in, const int* in_sizes, int n_in,
                              void* d_out, int out_size, void* d_ws, size_t ws_size,
                              hipStream_t stream) {
  (void)in_sizes; (void)n_in; (void)out_size; (void)ws_size;
  const float* x  = (const float*)d_in[0];
  const float* nw = (const float*)d_in[1];
  const float* Wq = (const float*)d_in[2];
  const float* Wk = (const float*)d_in[3];
  const float* Wv = (const float*)d_in[4];
  const float* Wo = (const float*)d_in[5];
  const float* W1 = (const float*)d_in[6];
  const float* W2 = (const float*)d_in[7];

  char* ws = (char*)d_ws;
  u16*   xn      = (u16*)(ws);                          //  8 MB  [4096][1024]
  u16*   wqkv1_t = (u16*)(ws + ((size_t)8  << 20));     // 14 MB  [7168][1024] Wq|Wk|Wv|W1 ^T
  u16*   bcat    = (u16*)(ws + ((size_t)22 << 20));     // 10 MB  [1024][5120] Wo^T|W2^T
  u16*   qkb     = (u16*)(ws + ((size_t)32 << 20));     // 16 MB  [4096][2048] (q|k)
  u16*   vtg     = (u16*)(ws + ((size_t)48 << 20));     //  8 MB  [32][64][2048] V^T
  u16*   acat    = (u16*)(ws + ((size_t)56 << 20));     // 40 MB  [4096][5120] attn_o|ff1
  float* dout    = (float*)d_out;                       // 16 MB  [4096][1024] fp32

  rmsnorm_k<<<BT, 256, 0, stream>>>(x, nw, xn, dout);
  const dim3 tb(32, 8);
  wtrans_k<<<dim3(32, 32),  tb, 0, stream>>>(Wq, wqkv1_t,                      1024, 1024, 1024, 0);
  wtrans_k<<<dim3(32, 32),  tb, 0, stream>>>(Wk, wqkv1_t + (size_t)1024*1024,  1024, 1024, 1024, 0);
  wtrans_k<<<dim3(32, 32),  tb, 0, stream>>>(Wv, wqkv1_t + (size_t)2048*1024,  1024, 1024, 1024, 0);
  wtrans_k<<<dim3(128, 32), tb, 0, stream>>>(W1, wqkv1_t + (size_t)3072*1024,  1024, 4096, 1024, 0);
  wtrans_k<<<dim3(32, 32),  tb, 0, stream>>>(Wo, bcat,                         1024, 1024, 5120, 0);
  wtrans_k<<<dim3(32, 128), tb, 0, stream>>>(W2, bcat,                         4096, 1024, 5120, 1024);

  gemm_fused<<<dim3(28, 16), 512, 0, stream>>>(xn, wqkv1_t, qkb, vtg, acat);
  attn_k<<<dim3(32, 64), 128, 0, stream>>>(qkb, vtg, acat);
  gemm_final<<<dim3(8, 64, 2), 256, 0, stream>>>(acat, bcat, dout);
}

// Round 14
// 349.256 us; speedup vs baseline: 1.0634x; 1.0077x over previous
//
#include <hip/hip_runtime.h>

#define DM   1024
#define DFF  4096
#define NH   16
#define HD   64
#define TT   2048
#define BT   4096   // B*T
#define KC   5120   // concat-K: 1024 (attn_o) + 4096 (ff1)

typedef unsigned short u16;
typedef unsigned int   u32;
typedef __attribute__((ext_vector_type(8))) short s16x8;
typedef __attribute__((ext_vector_type(4))) float f32x4;

__device__ __forceinline__ u16 f2bf(float f) {
  u32 u = __builtin_bit_cast(u32, f);
  u += 0x7fffu + ((u >> 16) & 1u);
  return (u16)(u >> 16);
}

// async global->LDS, 16B per lane. HW semantics: dest = wave-uniform base + lane*16.
__device__ __forceinline__ void gl2lds16(const void* g, void* l) {
  __builtin_amdgcn_global_load_lds((__attribute__((address_space(1))) void*)(g),
                                   (__attribute__((address_space(3))) void*)(l),
                                   16, 0, 0);
}

// raw barrier (no vmcnt(0) drain) + scheduler pin
#define S_BARRIER() do { __builtin_amdgcn_s_barrier(); __builtin_amdgcn_sched_barrier(0); } while (0)
#define VMWAIT(n)   asm volatile("s_waitcnt vmcnt(" #n ")" ::: "memory")

// ------- RMSNorm: x fp32 [BT][DM] -> xn bf16 ; also out = x (split-K base) -------
__global__ __launch_bounds__(256) void rmsnorm_k(const float* __restrict__ x,
                                                 const float* __restrict__ w,
                                                 u16* __restrict__ xn,
                                                 float* __restrict__ outx) {
  const int row = blockIdx.x;
  const int t = threadIdx.x;
  const float4 v = ((const float4*)(x + (size_t)row * DM))[t];
  ((float4*)(outx + (size_t)row * DM))[t] = v;   // out = x; gemm_final atomically adds
  float ss = v.x*v.x + v.y*v.y + v.z*v.z + v.w*v.w;
  #pragma unroll
  for (int off = 32; off; off >>= 1) ss += __shfl_xor(ss, off, 64);
  __shared__ float red[4];
  if ((t & 63) == 0) red[t >> 6] = ss;
  __syncthreads();
  const float tot = red[0] + red[1] + red[2] + red[3];
  const float r = __builtin_amdgcn_rsqf(tot * (1.0f / DM) + 1.1920929e-7f);
  const float4 wv = ((const float4*)w)[t];
  u16* o = xn + (size_t)row * DM + t * 4;
  o[0] = f2bf(v.x * r * wv.x);
  o[1] = f2bf(v.y * r * wv.y);
  o[2] = f2bf(v.z * r * wv.z);
  o[3] = f2bf(v.w * r * wv.w);
}

// --- weight transpose+cvt: W fp32 [K][N] -> Wt bf16 [n][pitch] at col-offset koff ---
__global__ __launch_bounds__(256) void wtrans_k(const float* __restrict__ W,
                                                u16* __restrict__ Wt,
                                                int K, int N, int pitch, int koff) {
  __shared__ float tile[32][33];
  const int n0 = blockIdx.x * 32, k0 = blockIdx.y * 32;
  const int tx = threadIdx.x, ty = threadIdx.y;  // (32,8)
  #pragma unroll
  for (int i = 0; i < 4; ++i)
    tile[ty + i*8][tx] = W[(size_t)(k0 + ty + i*8) * N + n0 + tx];
  __syncthreads();
  #pragma unroll
  for (int i = 0; i < 4; ++i)
    Wt[(size_t)(n0 + ty + i*8) * pitch + koff + k0 + tx] = f2bf(tile[tx][ty + i*8]);
}

// ---- fused QKV+FFN1 GEMM: A=xn [4096][1024], Bt [7168][1024] ----
// R3 8-phase schedule (unchanged since; measured ~95 us / 654 TF).
__global__ __launch_bounds__(512, 2) void gemm_fused(const u16* __restrict__ A,
                                                     const u16* __restrict__ Bt,
                                                     u16* __restrict__ qkb,
                                                     u16* __restrict__ vtg,
                                                     u16* __restrict__ acat) {
  const int K = 1024;
  __shared__ u16 sA[2 * 16384];   // 64 KB
  __shared__ u16 sB[2 * 16384];   // 64 KB
  const int t = threadIdx.x;               // 0..511
  const int lane = t & 63, wave = t >> 6;  // 8 waves
  const int quad = lane >> 4, l4 = lane & 15;
  const int wy = wave >> 2, wx = wave & 3; // wave grid 2(M) x 4(N); wave tile 128x64
  const size_t mBase = (size_t)blockIdx.y * 256;
  const size_t nBase = (size_t)blockIdx.x * 256;

  const int grow = t >> 3;                       // 0..63
  const int gchk = ((t & 7) ^ (grow & 7)) * 8;   // pre-swizzled source chunk
  const u16* AgR = A  + (mBase + grow) * K + gchk;
  const u16* BgR = Bt + (nBase + grow) * K + gchk;
  char* dA = (char*)sA;
  char* dB = (char*)sB;
  const int woff = wave * 1024;

  const int cs0 = ((quad)     ^ (l4 & 7)) * 8;   // kk=0
  const int cs1 = ((4 + quad) ^ (l4 & 7)) * 8;   // kk=1

  f32x4 acc[8][4];
  #pragma unroll
  for (int i = 0; i < 8; ++i)
    #pragma unroll
    for (int j = 0; j < 4; ++j)
      acc[i][j] = (f32x4)0.0f;

  s16x8 a[4][2], b[4][2];

  #define STG(p, slot, kt) do {                                                  \
    const int k0_ = (kt) * 64;                                                   \
    if ((p) == 0) {                                                              \
      gl2lds16(BgR + (size_t)0*64*K + k0_, dB + (slot)*32768 +     0 + woff);    \
      gl2lds16(BgR + (size_t)1*64*K + k0_, dB + (slot)*32768 +  8192 + woff);    \
    } else if ((p) == 1) {                                                       \
      gl2lds16(BgR + (size_t)2*64*K + k0_, dB + (slot)*32768 + 16384 + woff);    \
      gl2lds16(BgR + (size_t)3*64*K + k0_, dB + (slot)*32768 + 24576 + woff);    \
    } else if ((p) == 2) {                                                       \
      gl2lds16(AgR + (size_t)0*64*K + k0_, dA + (slot)*32768 +     0 + woff);    \
      gl2lds16(AgR + (size_t)2*64*K + k0_, dA + (slot)*32768 + 16384 + woff);    \
    } else {                                                                     \
      gl2lds16(AgR + (size_t)1*64*K + k0_, dA + (slot)*32768 +  8192 + woff);    \
      gl2lds16(AgR + (size_t)3*64*K + k0_, dA + (slot)*32768 + 24576 + woff);    \
    }                                                                            \
  } while (0)

  #define RDA(slot, qm) do {                                                     \
    const u16* p_ = sA + (slot)*16384 + wy*8192;                                 \
    _Pragma("unroll")                                                            \
    for (int m_ = 0; m_ < 4; ++m_) {                                             \
      const int ro_ = (((qm)*4 + m_)*16 + l4) * 64;                              \
      a[m_][0] = *(const s16x8*)&p_[ro_ + cs0];                                  \
      a[m_][1] = *(const s16x8*)&p_[ro_ + cs1];                                  \
    }                                                                            \
  } while (0)

  #define RDB(slot, qn) do {                                                     \
    const u16* p_ = sB + (slot)*16384 + (wx>>1)*8192 + (wx&1)*4096;              \
    _Pragma("unroll")                                                            \
    for (int n_ = 0; n_ < 2; ++n_) {                                             \
      const int ro_ = (((qn)*2 + n_)*16 + l4) * 64;                              \
      b[(qn)*2 + n_][0] = *(const s16x8*)&p_[ro_ + cs0];                         \
      b[(qn)*2 + n_][1] = *(const s16x8*)&p_[ro_ + cs1];                         \
    }                                                                            \
  } while (0)

  #define MM(qm, qn) do {                                                        \
    __builtin_amdgcn_s_setprio(1);                                               \
    _Pragma("unroll")                                                            \
    for (int m_ = 0; m_ < 4; ++m_)                                               \
      _Pragma("unroll")                                                          \
      for (int n_ = 0; n_ < 2; ++n_) {                                           \
        acc[(qm)*4+m_][(qn)*2+n_] = __builtin_amdgcn_mfma_f32_16x16x32_bf16(     \
            a[m_][0], b[(qn)*2+n_][0], acc[(qm)*4+m_][(qn)*2+n_], 0, 0, 0);      \
        acc[(qm)*4+m_][(qn)*2+n_] = __builtin_amdgcn_mfma_f32_16x16x32_bf16(     \
            a[m_][1], b[(qn)*2+n_][1], acc[(qm)*4+m_][(qn)*2+n_], 0, 0, 0);      \
      }                                                                          \
    __builtin_amdgcn_s_setprio(0);                                               \
  } while (0)

  STG(0, 0, 0); STG(1, 0, 0); STG(2, 0, 0); STG(3, 0, 0);
  VMWAIT(2);
  S_BARRIER();

  for (int i = 0; i < 7; ++i) {
    const int kt1 = 2*i + 1, kt2 = 2*i + 2;
    RDA(0,0); RDB(0,0); STG(0,1,kt1); S_BARRIER(); MM(0,0);            S_BARRIER();
    RDB(0,1);           STG(1,1,kt1); S_BARRIER(); MM(0,1); VMWAIT(4); S_BARRIER();
    RDA(0,1);           STG(2,1,kt1); S_BARRIER(); MM(1,0);            S_BARRIER();
                        STG(3,1,kt1); S_BARRIER(); MM(1,1); VMWAIT(2); S_BARRIER();
    RDA(1,0); RDB(1,0); STG(0,0,kt2); S_BARRIER(); MM(0,0);            S_BARRIER();
    RDB(1,1);           STG(1,0,kt2); S_BARRIER(); MM(0,1); VMWAIT(4); S_BARRIER();
    RDA(1,1);           STG(2,0,kt2); S_BARRIER(); MM(1,0);            S_BARRIER();
                        STG(3,0,kt2); S_BARRIER(); MM(1,1); VMWAIT(2); S_BARRIER();
  }
  RDA(0,0); RDB(0,0); STG(0,1,15); S_BARRIER(); MM(0,0);            S_BARRIER();
  RDB(0,1);           STG(1,1,15); S_BARRIER(); MM(0,1); VMWAIT(4); S_BARRIER();
  RDA(0,1);           STG(2,1,15); S_BARRIER(); MM(1,0);            S_BARRIER();
                      STG(3,1,15); S_BARRIER(); MM(1,1); VMWAIT(2); S_BARRIER();
  RDA(1,0); RDB(1,0);              S_BARRIER(); MM(0,0);            S_BARRIER();
  RDB(1,1);                        S_BARRIER(); MM(0,1); VMWAIT(0); S_BARRIER();
  RDA(1,1);                        S_BARRIER(); MM(1,0);            S_BARRIER();
                                   S_BARRIER(); MM(1,1);            S_BARRIER();

  #undef STG
  #undef RDA
  #undef RDB
  #undef MM

  #pragma unroll
  for (int i = 0; i < 8; ++i) {
    const size_t row0 = mBase + wy*128 + i*16 + quad*4;
    #pragma unroll
    for (int j = 0; j < 4; ++j) {
      const int col = (int)nBase + wx*64 + j*16 + l4;
      if (nBase < 1024) {               // Q: fold (1/sqrt(64))*log2(e)
        #pragma unroll
        for (int rg = 0; rg < 4; ++rg)
          qkb[(row0 + rg) * 2048 + col] = f2bf(acc[i][j][rg] * 0.18033688011f);
      } else if (nBase < 2048) {        // K
        #pragma unroll
        for (int rg = 0; rg < 4; ++rg)
          qkb[(row0 + rg) * 2048 + col] = f2bf(acc[i][j][rg]);
      } else if (nBase < 3072) {        // V: transposed, 4 tokens packed
        const int cv = col - 2048, hh = cv >> 6, dd = cv & 63;
        const int bb = (int)(row0 >> 11), t0 = (int)(row0 & 2047);
        ushort4 pk;
        pk.x = f2bf(acc[i][j][0]); pk.y = f2bf(acc[i][j][1]);
        pk.z = f2bf(acc[i][j][2]); pk.w = f2bf(acc[i][j][3]);
        *(ushort4*)(vtg + ((size_t)((bb*16 + hh)*64 + dd)) * 2048 + t0) = pk;
      } else {                          // FFN1: silu -> A_cat cols 1024..5119
        #pragma unroll
        for (int rg = 0; rg < 4; ++rg) {
          float v = acc[i][j][rg];
          v = v / (1.0f + __expf(-v));
          acat[(row0 + rg) * (size_t)KC + 1024 + (col - 3072)] = f2bf(v);
        }
      }
    }
  }
}

// ---- final GEMM: out += A_cat[4096][5120] * B_cat[1024][5120]^T (out pre-init = x) ----
// R14: split-K=2 (R10, measured -11 us) + 128x128 tile / 64x64 wave tile
// (R9's verified compute). R13 model: at 4 blocks/CU final became LDS-throughput
// bound; 32x64 wave tile reads 1125 B/MFMA. 64x64 wave tile reads 500 B/MFMA
// (8 ds_read_b128 per 16 MFMA); total LDS traffic 2.9 -> 1.97 GB. 3-slot ring
// (48 KB) -> 3 blocks/CU, 12 waves/CU (fixes R9's 1-block occupancy failure).
// Grid (8,32,2) = 512 blocks; 4 loads/wave/iter -> steady VMWAIT(4).
__global__ __launch_bounds__(256, 3) void gemm_final(const u16* __restrict__ A,
                                                     const u16* __restrict__ Bt,
                                                     float* __restrict__ out) {
  __shared__ u16 sA[3 * 128 * 32];   // 24 KB
  __shared__ u16 sB[3 * 128 * 32];   // 24 KB
  const int t = threadIdx.x;
  const int lane = t & 63, wave = t >> 6;
  const int quad = lane >> 4, l4 = lane & 15;
  const int wy = wave >> 1, wx = wave & 1;   // 2x2 wave grid; wave tile 64(M)x64(N)
  const int d  = blockIdx.x + (blockIdx.y << 3);   // 0..255 per K-half
  const int vb = ((d & 7) << 5) | (d >> 3);        // XCD -> 4 contiguous M-panels
  const int bx = vb & 7, by = vb >> 3;
  const size_t mBase = (size_t)by * 128;
  const size_t nBase = (size_t)bx * 128;
  const int kBase = (int)blockIdx.z * 2560;        // split-K half
  const int r  = t >> 2;          // 0..63 (row within 64-row G-load line)
  const int c8 = ((t & 3) ^ ((t >> 3) & 3)) * 8;   // pre-swizzled source chunk
  const int qsw = (quad ^ ((l4 >> 1) & 3)) * 8;    // swizzled read offset
  const u16* Ag0 = A  + (mBase + r) * KC + kBase + c8;
  const u16* Ag1 = Ag0 + (size_t)64 * KC;
  const u16* Bg0 = Bt + (nBase + r) * KC + kBase + c8;
  const u16* Bg1 = Bg0 + (size_t)64 * KC;
  char* sAb = (char*)sA + (wave << 10);
  char* sBb = (char*)sB + (wave << 10);

  f32x4 acc[4][4];
  #pragma unroll
  for (int i = 0; i < 4; ++i)
    #pragma unroll
    for (int j = 0; j < 4; ++j)
      acc[i][j] = (f32x4)0.0f;

  auto issue = [&](int sl, int k0) {
    gl2lds16(Ag0 + k0, sAb + sl*8192);           // A rows 0..63
    gl2lds16(Ag1 + k0, sAb + sl*8192 + 4096);    // A rows 64..127
    gl2lds16(Bg0 + k0, sBb + sl*8192);           // B rows 0..63
    gl2lds16(Bg1 + k0, sBb + sl*8192 + 4096);    // B rows 64..127
  };

  auto compute = [&](int sl) {
    const u16* pA = sA + sl * 4096;   // u16 elements: 128*32
    const u16* pB = sB + sl * 4096;
    s16x8 af[4], bfr[4];
    #pragma unroll
    for (int i = 0; i < 4; ++i)
      af[i] = *(const s16x8*)&pA[(wy*64 + i*16 + l4) * 32 + qsw];
    #pragma unroll
    for (int j = 0; j < 4; ++j)
      bfr[j] = *(const s16x8*)&pB[(wx*64 + j*16 + l4) * 32 + qsw];
    __builtin_amdgcn_s_setprio(1);
    #pragma unroll
    for (int i = 0; i < 4; ++i)
      #pragma unroll
      for (int j = 0; j < 4; ++j)
        acc[i][j] = __builtin_amdgcn_mfma_f32_16x16x32_bf16(af[i], bfr[j], acc[i][j], 0, 0, 0);
    __builtin_amdgcn_s_setprio(0);
  };

  const int NIT = 2560 / 32;   // 80 per K-half
  issue(0, 0); issue(1, 32);
  for (int kt = 0; kt < NIT - 2; ++kt) {
    VMWAIT(4);                    // my 4 loads for tile kt landed (kt+1's in flight)
    S_BARRIER();                  // all waves' tile-kt loads landed; kt-1 reads done
    issue((kt + 2) % 3, (kt + 2) * 32);   // slot of kt-1, freed by this barrier
    compute(kt % 3);
  }
  VMWAIT(4); S_BARRIER(); compute((NIT - 2) % 3);
  VMWAIT(0); S_BARRIER(); compute((NIT - 1) % 3);

  #pragma unroll
  for (int i = 0; i < 4; ++i) {
    const size_t row0 = mBase + wy*64 + i*16 + quad*4;
    #pragma unroll
    for (int j = 0; j < 4; ++j) {
      const int col = (int)nBase + wx*64 + j*16 + l4;
      #pragma unroll
      for (int rg = 0; rg < 4; ++rg)
        atomicAdd(out + (row0 + rg) * (size_t)DM + col, acc[i][j][rg]);
    }
  }
}

// ------- causal flash attention, fixed-max, in-block split-K=2 over waves -------
// R12 software pipeline (measured ~-4 us): K-frags double-buffered in regs,
// V issue moved before the QK MFMAs.
// writes bf16 into A_cat cols 0..1023 (pitch 5120)
__global__ __launch_bounds__(128) void attn_k(const u16* __restrict__ qk,
                                              const u16* __restrict__ vtg,
                                              u16* __restrict__ acat) {
  const int bh = blockIdx.x, b = bh >> 4, h = bh & 15;
  const int qt = 63 - blockIdx.y;
  const int qw = qt * 32;
  const int wave = threadIdx.x >> 6, lane = threadIdx.x & 63;
  const int quad = lane >> 4, l4 = lane & 15;
  const u16* Qp = qk + (size_t)b * TT * 2048 + h * HD;
  const u16* Kp = Qp + 1024;
  const u16* Vp = vtg + (size_t)bh * 64 * 2048;

  __shared__ u16 Pb[2][32][72];
  __shared__ float Ob[32][68];
  __shared__ float Lb[32];

  s16x8 qf[2][2];
  #pragma unroll
  for (int mi = 0; mi < 2; ++mi)
    #pragma unroll
    for (int kf = 0; kf < 2; ++kf)
      qf[mi][kf] = *(const s16x8*)(Qp + (size_t)(qw + mi*16 + l4) * 2048 + kf*32 + quad*8);

  const s16x8 ones = {0x3F80,0x3F80,0x3F80,0x3F80,0x3F80,0x3F80,0x3F80,0x3F80};

  f32x4 o[2][4];
  f32x4 lacc[2];
  #pragma unroll
  for (int mi = 0; mi < 2; ++mi) {
    lacc[mi] = (f32x4)0.0f;
    #pragma unroll
    for (int ni = 0; ni < 4; ++ni) o[mi][ni] = (f32x4)0.0f;
  }

  const int n   = (qt + 2) >> 1;
  const int n0  = (n + 1) >> 1;
  const int kt0 = wave ? n0 : 0;
  const int kt1 = wave ? n : n0;

  // load 8 K-fragments of tile ktv into register array KF
  #define LOADK(KF, ktv) do {                                                    \
    const int kk0_ = (ktv) * 64;                                                 \
    _Pragma("unroll")                                                            \
    for (int nj_ = 0; nj_ < 4; ++nj_) {                                          \
      const u16* kr_ = Kp + (size_t)(kk0_ + nj_*16 + l4) * 2048 + quad*8;        \
      KF[nj_*2]     = *(const s16x8*)kr_;                                        \
      KF[nj_*2 + 1] = *(const s16x8*)(kr_ + 32);                                 \
    }                                                                            \
  } while (0)

  // full k-tile body using K-fragments in KF
  #define KBODY(KF, ktv) do {                                                    \
    const int k0 = (ktv) * 64;                                                   \
    s16x8 vb[2][4];                                                              \
    _Pragma("unroll")                                                            \
    for (int kf2 = 0; kf2 < 2; ++kf2)                                            \
      _Pragma("unroll")                                                          \
      for (int ni = 0; ni < 4; ++ni)                                             \
        vb[kf2][ni] = *(const s16x8*)(Vp + (size_t)(ni*16 + l4) * 2048 + k0 + kf2*32 + quad*8); \
    f32x4 st[4][2];                                                              \
    _Pragma("unroll")                                                            \
    for (int nj = 0; nj < 4; ++nj)                                               \
      _Pragma("unroll")                                                          \
      for (int mi = 0; mi < 2; ++mi) {                                           \
        f32x4 aa = (f32x4)0.0f;                                                  \
        aa = __builtin_amdgcn_mfma_f32_16x16x32_bf16(KF[nj*2],   qf[mi][0], aa, 0, 0, 0); \
        aa = __builtin_amdgcn_mfma_f32_16x16x32_bf16(KF[nj*2+1], qf[mi][1], aa, 0, 0, 0); \
        st[nj][mi] = aa;                                                         \
      }                                                                          \
    if (k0 + 63 > qw) {                                                          \
      _Pragma("unroll")                                                          \
      for (int nj = 0; nj < 4; ++nj)                                             \
        _Pragma("unroll")                                                        \
        for (int mi = 0; mi < 2; ++mi)                                           \
          _Pragma("unroll")                                                      \
          for (int rg = 0; rg < 4; ++rg) {                                       \
            const int key = k0 + nj*16 + quad*4 + rg;                            \
            const int q   = qw + mi*16 + l4;                                     \
            if (key > q) st[nj][mi][rg] = -1e30f;                                \
          }                                                                      \
    }                                                                            \
    _Pragma("unroll")                                                            \
    for (int nj = 0; nj < 4; ++nj)                                               \
      _Pragma("unroll")                                                          \
      for (int mi = 0; mi < 2; ++mi) {                                           \
        float p0 = __builtin_amdgcn_exp2f(st[nj][mi][0]);                        \
        float p1 = __builtin_amdgcn_exp2f(st[nj][mi][1]);                        \
        float p2 = __builtin_amdgcn_exp2f(st[nj][mi][2]);                        \
        float p3 = __builtin_amdgcn_exp2f(st[nj][mi][3]);                        \
        uint2 w;                                                                 \
        w.x = __builtin_amdgcn_perm(__builtin_bit_cast(u32, p1),                 \
                                    __builtin_bit_cast(u32, p0), 0x07060302u);   \
        w.y = __builtin_amdgcn_perm(__builtin_bit_cast(u32, p3),                 \
                                    __builtin_bit_cast(u32, p2), 0x07060302u);   \
        *(uint2*)&Pb[wave][mi*16 + l4][nj*16 + quad*4] = w;                      \
      }                                                                          \
    _Pragma("unroll")                                                            \
    for (int kf2 = 0; kf2 < 2; ++kf2) {                                          \
      s16x8 pa[2];                                                               \
      _Pragma("unroll")                                                          \
      for (int mi = 0; mi < 2; ++mi)                                             \
        pa[mi] = *(const s16x8*)&Pb[wave][mi*16 + l4][kf2*32 + quad*8];          \
      _Pragma("unroll")                                                          \
      for (int mi = 0; mi < 2; ++mi) {                                           \
        lacc[mi] = __builtin_amdgcn_mfma_f32_16x16x32_bf16(pa[mi], ones, lacc[mi], 0, 0, 0); \
        _Pragma("unroll")                                                        \
        for (int ni = 0; ni < 4; ++ni)                                           \
          o[mi][ni] = __builtin_amdgcn_mfma_f32_16x16x32_bf16(pa[mi], vb[kf2][ni], o[mi][ni], 0, 0, 0); \
      }                                                                          \
    }                                                                            \
  } while (0)

  if (kt0 < kt1) {
    s16x8 kfA[8], kfB[8];
    LOADK(kfA, kt0);
    int kt = kt0;
    for (;;) {
      if (kt + 1 < kt1) LOADK(kfB, kt + 1);   // prefetch next tile's K
      KBODY(kfA, kt);
      ++kt;
      if (kt >= kt1) break;
      if (kt + 1 < kt1) LOADK(kfA, kt + 1);
      KBODY(kfB, kt);
      ++kt;
      if (kt >= kt1) break;
    }
  }

  #undef LOADK
  #undef KBODY

  if (wave == 1) {
    #pragma unroll
    for (int mi = 0; mi < 2; ++mi)
      #pragma unroll
      for (int rg = 0; rg < 4; ++rg) {
        const int row = mi*16 + quad*4 + rg;
        #pragma unroll
        for (int ni = 0; ni < 4; ++ni) Ob[row][ni*16 + l4] = o[mi][ni][rg];
        if (l4 == 0) Lb[row] = lacc[mi][rg];
      }
  }
  __syncthreads();
  if (wave == 0) {
    #pragma unroll
    for (int mi = 0; mi < 2; ++mi)
      #pragma unroll
      for (int rg = 0; rg < 4; ++rg) {
        const int row = mi*16 + quad*4 + rg;
        const float inv = 1.0f / (lacc[mi][rg] + Lb[row]);
        #pragma unroll
        for (int ni = 0; ni < 4; ++ni)
          Pb[0][row][ni*16 + l4] = f2bf((o[mi][ni][rg] + Ob[row][ni*16 + l4]) * inv);
      }
    #pragma unroll
    for (int it = 0; it < 4; ++it) {
      const int row = it*8 + (lane >> 3);
      const int c0  = (lane & 7) * 8;
      const s16x8 pk = *(const s16x8*)&Pb[0][row][c0];
      *(s16x8*)(acat + ((size_t)b * TT + qw + row) * KC + h*HD + c0) = pk;
    }
  }
}

extern "C" void kernel_launch(void* const* d_in, const int* in_sizes, int n_in,
                              void* d_out, int out_size, void* d_ws, size_t ws_size,
                              hipStream_t stream) {
  (void)in_sizes; (void)n_in; (void)out_size; (void)ws_size;
  const float* x  = (const float*)d_in[0];
  const float* nw = (const float*)d_in[1];
  const float* Wq = (const float*)d_in[2];
  const float* Wk = (const float*)d_in[3];
  const float* Wv = (const float*)d_in[4];
  const float* Wo = (const float*)d_in[5];
  const float* W1 = (const float*)d_in[6];
  const float* W2 = (const float*)d_in[7];

  char* ws = (char*)d_ws;
  u16*   xn      = (u16*)(ws);                          //  8 MB  [4096][1024]
  u16*   wqkv1_t = (u16*)(ws + ((size_t)8  << 20));     // 14 MB  [7168][1024] Wq|Wk|Wv|W1 ^T
  u16*   bcat    = (u16*)(ws + ((size_t)22 << 20));     // 10 MB  [1024][5120] Wo^T|W2^T
  u16*   qkb     = (u16*)(ws + ((size_t)32 << 20));     // 16 MB  [4096][2048] (q|k)
  u16*   vtg     = (u16*)(ws + ((size_t)48 << 20));     //  8 MB  [32][64][2048] V^T
  u16*   acat    = (u16*)(ws + ((size_t)56 << 20));     // 40 MB  [4096][5120] attn_o|ff1
  float* dout    = (float*)d_out;                       // 16 MB  [4096][1024] fp32

  rmsnorm_k<<<BT, 256, 0, stream>>>(x, nw, xn, dout);
  const dim3 tb(32, 8);
  wtrans_k<<<dim3(32, 32),  tb, 0, stream>>>(Wq, wqkv1_t,                      1024, 1024, 1024, 0);
  wtrans_k<<<dim3(32, 32),  tb, 0, stream>>>(Wk, wqkv1_t + (size_t)1024*1024,  1024, 1024, 1024, 0);
  wtrans_k<<<dim3(32, 32),  tb, 0, stream>>>(Wv, wqkv1_t + (size_t)2048*1024,  1024, 1024, 1024, 0);
  wtrans_k<<<dim3(128, 32), tb, 0, stream>>>(W1, wqkv1_t + (size_t)3072*1024,  1024, 4096, 1024, 0);
  wtrans_k<<<dim3(32, 32),  tb, 0, stream>>>(Wo, bcat,                         1024, 1024, 5120, 0);
  wtrans_k<<<dim3(32, 128), tb, 0, stream>>>(W2, bcat,                         4096, 1024, 5120, 1024);

  gemm_fused<<<dim3(28, 16), 512, 0, stream>>>(xn, wqkv1_t, qkb, vtg, acat);
  attn_k<<<dim3(32, 64), 128, 0, stream>>>(qkb, vtg, acat);
  gemm_final<<<dim3(8, 32, 2), 256, 0, stream>>>(acat, bcat, dout);
}